// Round 12
// baseline (660.652 us; speedup 1.0000x reference)
//
#include <hip/hip_runtime.h>
#include <hip/hip_bf16.h>

#define NEG_SLOPE 0.2f
#define EPSI 1e-5f
#define THR 8.0f

typedef __attribute__((ext_vector_type(8))) short bf16x8;
typedef __attribute__((ext_vector_type(4))) float f32x4;
typedef __attribute__((ext_vector_type(2))) float f32x2;

__device__ __forceinline__ float wred_sum(float v){
#pragma unroll
  for (int o = 32; o > 0; o >>= 1) v += __shfl_xor(v, o);
  return v;
}

__device__ __forceinline__ unsigned short f2bf(float f){
  __hip_bfloat16 h = __float2bfloat16(f);
  return *reinterpret_cast<unsigned short*>(&h);
}
__device__ __forceinline__ float bf2f(unsigned short u){
  return __uint_as_float((unsigned int)u << 16);
}
__device__ __forceinline__ f32x2 bfpair(unsigned int u){
  f32x2 r;
  r.x = __uint_as_float(u << 16);
  r.y = __uint_as_float(u & 0xffff0000u);
  return r;
}
__device__ __forceinline__ f32x2 vmax2(f32x2 a, f32x2 b){
#if __has_builtin(__builtin_elementwise_max)
  return __builtin_elementwise_max(a, b);
#else
  f32x2 r; r.x = fmaxf(a.x, b.x); r.y = fmaxf(a.y, b.y); return r;
#endif
}

__device__ __forceinline__ void gload16(const void* g, void* l){
  __builtin_amdgcn_global_load_lds((const __attribute__((address_space(1))) unsigned int*)g,
                                   (__attribute__((address_space(3))) unsigned int*)l, 16, 0, 0);
}

// ---------------- CSR build (by dst) ----------------
__global__ __launch_bounds__(256) void k_count(const int* __restrict__ ei, int* __restrict__ deg,
                                               int E, int EP){
  int e = blockIdx.x * 256 + threadIdx.x;
  if (e >= EP) return;
  int d = (e < E) ? ei[E + e] : (e - E);
  atomicAdd(&deg[d], 1);
}

__global__ __launch_bounds__(256) void k_scan(int* __restrict__ deg, int* __restrict__ rowptr, int n){
  __shared__ int part[256];
  int t = threadIdx.x;
  int L = (n + 255) / 256;
  int lo = t * L, hi = min(lo + L, n);
  int s = 0;
  for (int i = lo; i < hi; i++) s += deg[i];
  part[t] = s;
  __syncthreads();
  if (t == 0){
    int acc = 0;
    for (int i = 0; i < 256; i++){ int v = part[i]; part[i] = acc; acc += v; }
  }
  __syncthreads();
  int acc = part[t];
  for (int i = lo; i < hi; i++){
    int d = deg[i];
    rowptr[i] = acc;
    deg[i] = acc;
    acc += d;
  }
  if (t == 255) rowptr[n] = acc;
}

__global__ __launch_bounds__(256) void k_fill(const int* __restrict__ ei, int* __restrict__ cursor,
                                              int* __restrict__ srcn, int E, int EP){
  int e = blockIdx.x * 256 + threadIdx.x;
  if (e >= EP) return;
  int s, d;
  if (e < E){ s = ei[e]; d = ei[E + e]; } else { s = d = e - E; }
  int pos = atomicAdd(&cursor[d], 1);
  srcn[pos] = s;
}

// ---------------- bf16 weight transposes ----------------
__global__ __launch_bounds__(256) void k_cvt_wt(const float* __restrict__ W,
                                                unsigned short* __restrict__ Wt,
                                                int K, int Ncol){
  __shared__ float t[32][33];
  int bx = blockIdx.x, by = blockIdx.y;
  int tx = threadIdx.x & 31, ty = threadIdx.x >> 5;
#pragma unroll
  for (int i = 0; i < 4; i++)
    t[ty + i * 8][tx] = W[(size_t)(by * 32 + ty + i * 8) * Ncol + bx * 32 + tx];
  __syncthreads();
#pragma unroll
  for (int i = 0; i < 4; i++)
    Wt[(size_t)(bx * 32 + ty + i * 8) * K + by * 32 + tx] = f2bf(t[tx][ty + i * 8]);
}

__global__ __launch_bounds__(256) void k_cvt_wt2(const float* __restrict__ Wa,
                                                 const float* __restrict__ Wb,
                                                 unsigned short* __restrict__ Wt,
                                                 int K, int Ncol){
  __shared__ float t[32][33];
  int half = gridDim.x >> 1;
  int isB = blockIdx.x >= half;
  const float* W = isB ? Wb : Wa;
  unsigned short* out = Wt + (isB ? (size_t)Ncol * K : 0);
  int bx = isB ? blockIdx.x - half : blockIdx.x;
  int by = blockIdx.y;
  int tx = threadIdx.x & 31, ty = threadIdx.x >> 5;
#pragma unroll
  for (int i = 0; i < 4; i++)
    t[ty + i * 8][tx] = W[(size_t)(by * 32 + ty + i * 8) * Ncol + bx * 32 + tx];
  __syncthreads();
#pragma unroll
  for (int i = 0; i < 4; i++)
    out[(size_t)(bx * 32 + ty + i * 8) * K + by * 32 + tx] = f2bf(t[tx][ty + i * 8]);
}

// ---------------- bf16 MFMA GEMM, BK=64 2-phase, 128x256 tile, 8 waves ----------------
__global__ __launch_bounds__(512) void k_gemm_b64(const unsigned short* __restrict__ A,
                                                  const unsigned short* __restrict__ Wt,
                                                  const float* __restrict__ ba,
                                                  const float* __restrict__ bb,
                                                  int bsplit,
                                                  unsigned short* __restrict__ Cb,
                                                  int M, int K, int Ncol){
  __shared__ unsigned short As[128 * 64];
  __shared__ unsigned short Bs[256 * 64];
  const int tid = threadIdx.x;
  const int w = tid >> 6, lane = tid & 63;
  const int wr = w >> 2, wc = w & 3;
  const int row0 = blockIdx.y * 128, col0 = blockIdx.x * 256;
  const int lr = lane & 15, lk = lane >> 4;

  f32x4 acc[4][4];
#pragma unroll
  for (int i = 0; i < 4; i++)
#pragma unroll
    for (int j = 0; j < 4; j++) acc[i][j] = (f32x4){0.f, 0.f, 0.f, 0.f};

  for (int k0 = 0; k0 < K; k0 += 64){
#pragma unroll
    for (int t = 0; t < 2; t++){
      int g = w * 64 + lane + t * 512;
      int row = g >> 3, slot = g & 7;
      int kq = slot ^ ((row >> 1) & 7);
      int srow = row0 + row; if (srow >= M) srow = M - 1;
      gload16(&A[(size_t)srow * K + k0 + kq * 8], &As[(size_t)(w * 64 + t * 512) * 8]);
    }
#pragma unroll
    for (int t = 0; t < 4; t++){
      int g = w * 64 + lane + t * 512;
      int col = g >> 3, slot = g & 7;
      int kq = slot ^ ((col >> 1) & 7);
      gload16(&Wt[(size_t)(col0 + col) * K + k0 + kq * 8], &Bs[(size_t)(w * 64 + t * 512) * 8]);
    }
    __syncthreads();

#pragma unroll
    for (int ph = 0; ph < 2; ph++){
      bf16x8 af[4], bf_[4];
#pragma unroll
      for (int mi = 0; mi < 4; mi++){
        int rl = wr * 64 + mi * 16 + lr;
        int sl = (ph * 4 + lk) ^ ((rl >> 1) & 7);
        af[mi] = *(const bf16x8*)&As[(rl * 8 + sl) * 8];
      }
#pragma unroll
      for (int ni = 0; ni < 4; ni++){
        int cl = wc * 64 + ni * 16 + lr;
        int sl = (ph * 4 + lk) ^ ((cl >> 1) & 7);
        bf_[ni] = *(const bf16x8*)&Bs[(cl * 8 + sl) * 8];
      }
#pragma unroll
      for (int mi = 0; mi < 4; mi++)
#pragma unroll
        for (int ni = 0; ni < 4; ni++)
          acc[mi][ni] = __builtin_amdgcn_mfma_f32_16x16x32_bf16(af[mi], bf_[ni], acc[mi][ni], 0, 0, 0);
    }
    __syncthreads();
  }

#pragma unroll
  for (int mi = 0; mi < 4; mi++){
#pragma unroll
    for (int ni = 0; ni < 4; ni++){
      int gc = col0 + wc * 64 + ni * 16 + lr;
      float bv = gc < bsplit ? ba[gc] : bb[gc - bsplit];
#pragma unroll
      for (int r = 0; r < 4; r++){
        int gr = row0 + wr * 64 + mi * 16 + lk * 4 + r;
        if (gr < M) Cb[(size_t)gr * Ncol + gc] = f2bf(acc[mi][ni][r] + bv);
      }
    }
  }
}

// ---------------- bf16 MFMA GEMM, 8 waves, 128 x BN tile, BK=32 (L4) ----------------
template<int BN>
__global__ __launch_bounds__(512) void k_gemm_mfma8(const unsigned short* __restrict__ A,
                                                    const unsigned short* __restrict__ Wt,
                                                    const float* __restrict__ ba,
                                                    const float* __restrict__ bb,
                                                    int bsplit,
                                                    unsigned short* __restrict__ Cb,
                                                    int M, int K, int Ncol){
  constexpr int NF = BN / 64;
  __shared__ unsigned short As[128 * 32];
  __shared__ unsigned short Bs[BN * 32];
  const int tid = threadIdx.x;
  const int w = tid >> 6, lane = tid & 63;
  const int wr = w >> 2, wc = w & 3;
  const int row0 = blockIdx.y * 128, col0 = blockIdx.x * BN;
  const int lr = lane & 15, lk = lane >> 4;
  const int swz = (lr >> 1) & 3;

  f32x4 acc[4][NF];
#pragma unroll
  for (int i = 0; i < 4; i++)
#pragma unroll
    for (int j = 0; j < NF; j++) acc[i][j] = (f32x4){0.f, 0.f, 0.f, 0.f};

  for (int k0 = 0; k0 < K; k0 += 32){
    for (int g0 = w * 64; g0 < 512; g0 += 512){
      int g = g0 + lane;
      int row = g >> 2, slot = g & 3;
      int kq = slot ^ ((row >> 1) & 3);
      int srow = row0 + row; if (srow >= M) srow = M - 1;
      gload16(&A[(size_t)srow * K + k0 + kq * 8], &As[(size_t)g0 * 8]);
    }
    for (int g0 = w * 64; g0 < BN * 4; g0 += 512){
      int g = g0 + lane;
      int col = g >> 2, slot = g & 3;
      int kq = slot ^ ((col >> 1) & 3);
      gload16(&Wt[(size_t)(col0 + col) * K + k0 + kq * 8], &Bs[(size_t)g0 * 8]);
    }
    __syncthreads();

    bf16x8 af[4], bf_[NF];
#pragma unroll
    for (int mi = 0; mi < 4; mi++){
      int rl = wr * 64 + mi * 16 + lr;
      af[mi] = *(const bf16x8*)&As[(rl * 4 + (lk ^ swz)) * 8];
    }
#pragma unroll
    for (int ni = 0; ni < NF; ni++){
      int cl = wc * (BN / 4) + ni * 16 + lr;
      bf_[ni] = *(const bf16x8*)&Bs[(cl * 4 + (lk ^ swz)) * 8];
    }
#pragma unroll
    for (int mi = 0; mi < 4; mi++)
#pragma unroll
      for (int ni = 0; ni < NF; ni++)
        acc[mi][ni] = __builtin_amdgcn_mfma_f32_16x16x32_bf16(af[mi], bf_[ni], acc[mi][ni], 0, 0, 0);
    __syncthreads();
  }

#pragma unroll
  for (int mi = 0; mi < 4; mi++){
#pragma unroll
    for (int ni = 0; ni < NF; ni++){
      int gc = col0 + wc * (BN / 4) + ni * 16 + lr;
      float bv = gc < bsplit ? ba[gc] : bb[gc - bsplit];
#pragma unroll
      for (int r = 0; r < 4; r++){
        int gr = row0 + wr * 64 + mi * 16 + lk * 4 + r;
        if (gr < M) Cb[(size_t)gr * Ncol + gc] = f2bf(acc[mi][ni][r] + bv);
      }
    }
  }
}

// ---------------- text-proj GEMM: fp32 A reg-staged -> bf16 LDS; BM=64, Ncol=64 ----------------
// 8 waves: wr = w>>2 (2 row groups of 32), wc = w&3 (4 col groups of 16).
__global__ __launch_bounds__(512) void k_gemm_tp(const float* __restrict__ A,
                                                 const unsigned short* __restrict__ Wt,
                                                 const float* __restrict__ bias,
                                                 unsigned short* __restrict__ Cb,
                                                 int M, int K){
  __shared__ unsigned short As[64 * 32];
  __shared__ unsigned short Bs[64 * 32];
  const int tid = threadIdx.x;
  const int w = tid >> 6, lane = tid & 63;
  const int wr = w >> 2, wc = w & 3;
  const int row0 = blockIdx.y * 64;
  const int lr = lane & 15, lk = lane >> 4;
  const int swz = (lr >> 1) & 3;

  f32x4 acc[2];
  acc[0] = (f32x4){0.f, 0.f, 0.f, 0.f};
  acc[1] = (f32x4){0.f, 0.f, 0.f, 0.f};

  for (int k0 = 0; k0 < K; k0 += 32){
    if (tid < 256){
      int g = tid;                       // A granule 0..255 (64 rows x 4 slots)
      int row = g >> 2, slot = g & 3;
      int kq = slot ^ ((row >> 1) & 3);
      int srow = row0 + row; if (srow >= M) srow = M - 1;
      const float* ap = &A[(size_t)srow * K + k0 + kq * 8];
      float4 f0 = *(const float4*)ap;
      float4 f1 = *(const float4*)(ap + 4);
      bf16x8 v;
      v[0] = (short)f2bf(f0.x); v[1] = (short)f2bf(f0.y);
      v[2] = (short)f2bf(f0.z); v[3] = (short)f2bf(f0.w);
      v[4] = (short)f2bf(f1.x); v[5] = (short)f2bf(f1.y);
      v[6] = (short)f2bf(f1.z); v[7] = (short)f2bf(f1.w);
      *(bf16x8*)&As[(size_t)g * 8] = v;
    } else {
      int g = tid - 256;                 // B granule 0..255
      int col = g >> 2, slot = g & 3;
      int kq = slot ^ ((col >> 1) & 3);
      gload16(&Wt[(size_t)col * K + k0 + kq * 8], &Bs[(size_t)g * 8]);
    }
    __syncthreads();

    bf16x8 af[2], bfr;
#pragma unroll
    for (int mi = 0; mi < 2; mi++){
      int rl = wr * 32 + mi * 16 + lr;
      af[mi] = *(const bf16x8*)&As[(rl * 4 + (lk ^ swz)) * 8];
    }
    {
      int cl = wc * 16 + lr;
      bfr = *(const bf16x8*)&Bs[(cl * 4 + (lk ^ swz)) * 8];
    }
    acc[0] = __builtin_amdgcn_mfma_f32_16x16x32_bf16(af[0], bfr, acc[0], 0, 0, 0);
    acc[1] = __builtin_amdgcn_mfma_f32_16x16x32_bf16(af[1], bfr, acc[1], 0, 0, 0);
    __syncthreads();
  }

  int gc = wc * 16 + lr;
  float bv = bias[gc];
#pragma unroll
  for (int mi = 0; mi < 2; mi++)
#pragma unroll
    for (int r = 0; r < 4; r++){
      int gr = row0 + wr * 32 + mi * 16 + lk * 4 + r;
      if (gr < M) Cb[(size_t)gr * 64 + gc] = f2bf(acc[mi][r] + bv);
    }
}

// ---------------- fused GATv2 edge phase, 8 heads (single-wave, dual-state, defer-max) ----------------
__global__ __launch_bounds__(256, 8) void k_gat_fused8(const unsigned short* __restrict__ xlrb,
                                                       const float* __restrict__ att,
                                                       const int* __restrict__ rowptr,
                                                       const int* __restrict__ srcn,
                                                       const float* __restrict__ bias,
                                                       const unsigned short* __restrict__ resb,
                                                       unsigned short* __restrict__ yb,
                                                       int N){
  int node = (blockIdx.x * 256 + threadIdx.x) >> 6;
  int lane = threadIdx.x & 63;
  if (node >= N) return;
  f32x2 xr2[4], av2[4];
  {
    uint4 ur = *(const uint4*)&xlrb[(size_t)node * 1024 + 512 + lane * 8];
    xr2[0] = bfpair(ur.x); xr2[1] = bfpair(ur.y); xr2[2] = bfpair(ur.z); xr2[3] = bfpair(ur.w);
    float4 a0 = *(const float4*)&att[lane * 8];
    float4 a1 = *(const float4*)&att[lane * 8 + 4];
    av2[0] = (f32x2){a0.x, a0.y}; av2[1] = (f32x2){a0.z, a0.w};
    av2[2] = (f32x2){a1.x, a1.y}; av2[3] = (f32x2){a1.z, a1.w};
  }
  int e0 = rowptr[node], e1 = rowptr[node + 1];
  float m0 = -1e30f, s0 = 0.f, m1 = -1e30f, s1 = 0.f;
  f32x2 acc0[4] = {}, acc1[4] = {};

  for (int base = e0; base < e1; base += 64){
    int cnt = min(64, e1 - base);
    int sn = 0;
    if (lane < cnt) sn = srcn[base + lane];
    int k = 0;
    for (; k + 1 < cnt; k += 2){
      int ska = __shfl(sn, k);
      int skb = __shfl(sn, k + 1);
      uint4 ua = *(const uint4*)&xlrb[(size_t)ska * 1024 + lane * 8];
      uint4 ub = *(const uint4*)&xlrb[(size_t)skb * 1024 + lane * 8];
      f32x2 va[4], vb[4];
      va[0] = bfpair(ua.x); va[1] = bfpair(ua.y); va[2] = bfpair(ua.z); va[3] = bfpair(ua.w);
      vb[0] = bfpair(ub.x); vb[1] = bfpair(ub.y); vb[2] = bfpair(ub.z); vb[3] = bfpair(ub.w);
      f32x2 da = (f32x2){0.f, 0.f}, db = (f32x2){0.f, 0.f};
#pragma unroll
      for (int j = 0; j < 4; j++){
        f32x2 ta = va[j] + xr2[j];
        f32x2 tb = vb[j] + xr2[j];
        ta = vmax2(ta, ta * NEG_SLOPE);
        tb = vmax2(tb, tb * NEG_SLOPE);
        da += ta * av2[j];
        db += tb * av2[j];
      }
      float suma = da.x + da.y, sumb = db.x + db.y;
      suma += __shfl_xor(suma, 1); sumb += __shfl_xor(sumb, 1);
      suma += __shfl_xor(suma, 2); sumb += __shfl_xor(sumb, 2);
      suma += __shfl_xor(suma, 4); sumb += __shfl_xor(sumb, 4);
      if (__builtin_expect(__any(suma > m0 + THR), 0)){
        float mn = fmaxf(m0, suma);
        float cs = __expf(m0 - mn);
        float p  = __expf(suma - mn);
        s0 = s0 * cs + p;
#pragma unroll
        for (int j = 0; j < 4; j++) acc0[j] = acc0[j] * cs + va[j] * p;
        m0 = mn;
      } else {
        float p = __expf(suma - m0);
        s0 += p;
#pragma unroll
        for (int j = 0; j < 4; j++) acc0[j] += va[j] * p;
      }
      if (__builtin_expect(__any(sumb > m1 + THR), 0)){
        float mn = fmaxf(m1, sumb);
        float cs = __expf(m1 - mn);
        float p  = __expf(sumb - mn);
        s1 = s1 * cs + p;
#pragma unroll
        for (int j = 0; j < 4; j++) acc1[j] = acc1[j] * cs + vb[j] * p;
        m1 = mn;
      } else {
        float p = __expf(sumb - m1);
        s1 += p;
#pragma unroll
        for (int j = 0; j < 4; j++) acc1[j] += vb[j] * p;
      }
    }
    if (k < cnt){
      int ska = __shfl(sn, k);
      uint4 ua = *(const uint4*)&xlrb[(size_t)ska * 1024 + lane * 8];
      f32x2 va[4];
      va[0] = bfpair(ua.x); va[1] = bfpair(ua.y); va[2] = bfpair(ua.z); va[3] = bfpair(ua.w);
      f32x2 da = (f32x2){0.f, 0.f};
#pragma unroll
      for (int j = 0; j < 4; j++){
        f32x2 ta = va[j] + xr2[j];
        ta = vmax2(ta, ta * NEG_SLOPE);
        da += ta * av2[j];
      }
      float suma = da.x + da.y;
      suma += __shfl_xor(suma, 1);
      suma += __shfl_xor(suma, 2);
      suma += __shfl_xor(suma, 4);
      if (__builtin_expect(__any(suma > m0 + THR), 0)){
        float mn = fmaxf(m0, suma);
        float cs = __expf(m0 - mn);
        float p  = __expf(suma - mn);
        s0 = s0 * cs + p;
#pragma unroll
        for (int j = 0; j < 4; j++) acc0[j] = acc0[j] * cs + va[j] * p;
        m0 = mn;
      } else {
        float p = __expf(suma - m0);
        s0 += p;
#pragma unroll
        for (int j = 0; j < 4; j++) acc0[j] += va[j] * p;
      }
    }
  }
  float m = fmaxf(m0, m1);
  float c0 = __expf(m0 - m), c1 = __expf(m1 - m);
  float s = s0 * c0 + s1 * c1;
  float inv = 1.f / s;
  float4 b0 = *(const float4*)&bias[lane * 8];
  float4 b1 = *(const float4*)&bias[lane * 8 + 4];
  f32x2 bi2[4] = {(f32x2){b0.x, b0.y}, (f32x2){b0.z, b0.w},
                  (f32x2){b1.x, b1.y}, (f32x2){b1.z, b1.w}};
  f32x2 re2[4] = {};
  size_t o = (size_t)node * 512 + lane * 8;
  if (resb){
    uint4 rr = *(const uint4*)&resb[o];
    re2[0] = bfpair(rr.x); re2[1] = bfpair(rr.y); re2[2] = bfpair(rr.z); re2[3] = bfpair(rr.w);
  }
  bf16x8 ov;
#pragma unroll
  for (int j = 0; j < 4; j++){
    f32x2 r = (acc0[j] * c0 + acc1[j] * c1) * inv + bi2[j] + re2[j];
    ov[2 * j]     = (short)f2bf(r.x);
    ov[2 * j + 1] = (short)f2bf(r.y);
  }
  *(bf16x8*)&yb[o] = ov;
}

// ---------------- fused GATv2 edge phase, 1 head, OD=64 (layer 4, quad-state) ----------------
__global__ __launch_bounds__(256) void k_gat_fused1(const unsigned short* __restrict__ xlr,
                                                    const float* __restrict__ att,
                                                    const int* __restrict__ rowptr,
                                                    const int* __restrict__ srcn,
                                                    const float* __restrict__ bias,
                                                    unsigned short* __restrict__ yb4,
                                                    int N){
  int node = (blockIdx.x * 256 + threadIdx.x) >> 6;
  int lane = threadIdx.x & 63;
  if (node >= N) return;
  float xrv = bf2f(xlr[(size_t)node * 128 + 64 + lane]);
  float attv = att[lane];
  int e0 = rowptr[node], e1 = rowptr[node + 1];
  float m[4] = {-1e30f, -1e30f, -1e30f, -1e30f};
  float s[4] = {0.f, 0.f, 0.f, 0.f};
  float acc[4] = {0.f, 0.f, 0.f, 0.f};
  for (int base = e0; base < e1; base += 64){
    int cnt = min(64, e1 - base);
    int sn = 0;
    if (lane < cnt) sn = srcn[base + lane];
    for (int k = 0; k < cnt; k += 4){
#pragma unroll
      for (int j = 0; j < 4; j++){
        if (k + j < cnt){
          int sk = __shfl(sn, k + j);
          float v = bf2f(xlr[(size_t)sk * 128 + lane]);
          float t = v + xrv;
          t = fmaxf(t, t * NEG_SLOPE);
          float sum = wred_sum(t * attv);
          if (sum > m[j] + THR){
            float mn = fmaxf(m[j], sum);
            float cs = __expf(m[j] - mn);
            float p  = __expf(sum - mn);
            s[j] = s[j] * cs + p;
            acc[j] = acc[j] * cs + p * v;
            m[j] = mn;
          } else {
            float p = __expf(sum - m[j]);
            s[j] += p;
            acc[j] += p * v;
          }
        }
      }
    }
  }
  float mm = fmaxf(fmaxf(m[0], m[1]), fmaxf(m[2], m[3]));
  float st = 0.f, at = 0.f;
#pragma unroll
  for (int j = 0; j < 4; j++){
    float c = __expf(m[j] - mm);
    st += s[j] * c;
    at += acc[j] * c;
  }
  yb4[(size_t)node * 64 + lane] = f2bf(at / st + bias[lane]);
}

// ---------------- GraphNorm: chunked stats (bf16 in) -> coef -> apply (bf16 in/out + cat) ----------------
#define NCHUNK 16
__global__ __launch_bounds__(256) void k_gnorm_stats(const unsigned short* __restrict__ y,
                                                     const int* __restrict__ ptrg,
                                                     float* __restrict__ psum,
                                                     float* __restrict__ psq,
                                                     int OD){
  int g = blockIdx.x, chunk = blockIdx.z;
  int lane = threadIdx.x & 63, sub = threadIdx.x >> 6;
  int c = blockIdx.y * 64 + lane;
  int lo = ptrg[g], hi = ptrg[g + 1], len = hi - lo;
  int c0 = lo + (len * chunk) / NCHUNK, c1 = lo + (len * (chunk + 1)) / NCHUNK;
  float s = 0.f, q = 0.f;
  for (int i = c0 + sub; i < c1; i += 4){
    float v = bf2f(y[(size_t)i * OD + c]);
    s += v; q += v * v;
  }
  __shared__ float sm[4][64], sq2[4][64];
  sm[sub][lane] = s; sq2[sub][lane] = q;
  __syncthreads();
  if (sub == 0){
    s = sm[0][lane] + sm[1][lane] + sm[2][lane] + sm[3][lane];
    q = sq2[0][lane] + sq2[1][lane] + sq2[2][lane] + sq2[3][lane];
    size_t o = (size_t)(g * NCHUNK + chunk) * OD + c;
    psum[o] = s; psq[o] = q;
  }
}

__global__ __launch_bounds__(256) void k_gnorm_coef(const float* __restrict__ psum,
                                                    const float* __restrict__ psq,
                                                    const float* __restrict__ w,
                                                    const float* __restrict__ b,
                                                    const float* __restrict__ ms,
                                                    const int* __restrict__ ptrg,
                                                    float* __restrict__ cA,
                                                    float* __restrict__ cC,
                                                    int OD){
  int g = blockIdx.x;
  int len = ptrg[g + 1] - ptrg[g];
  float inv_n = 1.f / (float)len;
  for (int c = threadIdx.x; c < OD; c += 256){
    float s = 0.f, q = 0.f;
    for (int k = 0; k < NCHUNK; k++){
      size_t o = (size_t)(g * NCHUNK + k) * OD + c;
      s += psum[o]; q += psq[o];
    }
    float mean = s * inv_n, ey2 = q * inv_n;
    float m = ms[c];
    float var = ey2 - mean * mean * (2.f * m - m * m);
    float inv = rsqrtf(var + EPSI);
    float A = w[c] * inv;
    cA[(size_t)g * OD + c] = A;
    cC[(size_t)g * OD + c] = b[c] - A * m * mean;
  }
}

__global__ __launch_bounds__(256) void k_gnorm_apply(const unsigned short* __restrict__ y,
                                                     const int* __restrict__ batch,
                                                     const float* __restrict__ cA,
                                                     const float* __restrict__ cC,
                                                     unsigned short* __restrict__ outb,
                                                     const int* __restrict__ ptrg,
                                                     float* __restrict__ cat,
                                                     int catoff, int FD,
                                                     int OD, int total4, int do_elu){
  int idx = blockIdx.x * 256 + threadIdx.x;
  if (idx >= total4) return;
  int od4 = OD >> 2;
  int node = idx / od4;
  int c = (idx - node * od4) << 2;
  int g = batch[node];
  ushort4 uv = ((const ushort4*)y)[idx];
  float4 v = make_float4(bf2f(uv.x), bf2f(uv.y), bf2f(uv.z), bf2f(uv.w));
  float4 A = *(const float4*)&cA[(size_t)g * OD + c];
  float4 Cc = *(const float4*)&cC[(size_t)g * OD + c];
  float4 r;
  r.x = A.x * v.x + Cc.x;
  r.y = A.y * v.y + Cc.y;
  r.z = A.z * v.z + Cc.z;
  r.w = A.w * v.w + Cc.w;
  if (do_elu){
    r.x = r.x > 0.f ? r.x : expf(r.x) - 1.f;
    r.y = r.y > 0.f ? r.y : expf(r.y) - 1.f;
    r.z = r.z > 0.f ? r.z : expf(r.z) - 1.f;
    r.w = r.w > 0.f ? r.w : expf(r.w) - 1.f;
  }
  ushort4 ob;
  ob.x = f2bf(r.x); ob.y = f2bf(r.y); ob.z = f2bf(r.z); ob.w = f2bf(r.w);
  ((ushort4*)outb)[idx] = ob;
  if (node == ptrg[g])
    *(float4*)&cat[(size_t)g * FD + catoff + c] = r;
}

// ---------------- final linear on 50 summary rows ----------------
__global__ __launch_bounds__(256) void k_final(const float* __restrict__ cat,
                                               const float* __restrict__ lin_w,
                                               const float* __restrict__ lin_b,
                                               float* __restrict__ out, int FD){
  int g = blockIdx.x;
  float s = 0.f;
  for (int c = threadIdx.x; c < FD; c += 256) s += cat[(size_t)g * FD + c] * lin_w[c];
  s = wred_sum(s);
  __shared__ float sm[4];
  if ((threadIdx.x & 63) == 0) sm[threadIdx.x >> 6] = s;
  __syncthreads();
  if (threadIdx.x == 0) out[g] = sm[0] + sm[1] + sm[2] + sm[3] + lin_b[0];
}

extern "C" void kernel_launch(void* const* d_in, const int* in_sizes, int n_in,
                              void* d_out, int out_size, void* d_ws, size_t ws_size,
                              hipStream_t stream) {
  const int TD = 768, HC = 64, H = 8;
  const float* x     = (const float*)d_in[0];
  const int*   ei    = (const int*)d_in[1];
  const int*   batch = (const int*)d_in[2];
  const int*   ptrg  = (const int*)d_in[3];
  const float* tp_w  = (const float*)d_in[4];
  const float* tp_b  = (const float*)d_in[5];
  const float* lin_w = (const float*)d_in[6];
  const float* lin_b = (const float*)d_in[7];
  const float* cw[4][6];
  for (int l = 0; l < 4; l++)
    for (int j = 0; j < 6; j++) cw[l][j] = (const float*)d_in[8 + 6 * l + j];
  const float* nw[4][3];
  for (int l = 0; l < 4; l++)
    for (int j = 0; j < 3; j++) nw[l][j] = (const float*)d_in[32 + 3 * l + j];

  const int N  = in_sizes[0] / TD;   // 20000
  const int E  = in_sizes[1] / 2;    // 240000
  const int EP = E + N;              // 260000
  const int G  = in_sizes[3] - 1;    // 50
  const int FD = 3 * HC * H + HC;    // 1600

  char* wsp = (char*)d_ws;
  size_t off = 0;
  auto alloc = [&](size_t b) -> void* {
    void* p = wsp + off;
    off += (b + 255) & ~(size_t)255;
    return p;
  };
  unsigned short* xlrb = (unsigned short*)alloc((size_t)N * 1024 * 2);
  unsigned short* yb   = (unsigned short*)alloc((size_t)N * 512 * 2);
  unsigned short* actA = (unsigned short*)alloc((size_t)N * 512 * 2);
  unsigned short* h0h  = (unsigned short*)alloc((size_t)N * 64 * 2);
  int*   rowptr= (int*)alloc((size_t)(N + 1) * 4);
  int*   cursor= (int*)alloc((size_t)N * 4);
  int*   srcn  = (int*)alloc((size_t)EP * 4);
  float* cat   = (float*)alloc((size_t)G * FD * 4);
  float* psum  = (float*)alloc((size_t)G * NCHUNK * 512 * 4);
  float* psq   = (float*)alloc((size_t)G * NCHUNK * 512 * 4);
  float* cA    = (float*)alloc((size_t)G * 512 * 4);
  float* cC    = (float*)alloc((size_t)G * 512 * 4);
  unsigned short* WtLR = (unsigned short*)alloc((size_t)1024 * 512 * 2);
  unsigned short* WtTP = (unsigned short*)alloc((size_t)64 * 768 * 2);
  unsigned short* Wt4  = (unsigned short*)alloc((size_t)128 * 512 * 2);
  (void)ws_size; (void)n_in; (void)out_size;

  float* out = (float*)d_out;

  unsigned short* xlr4b = xlrb;
  unsigned short* yb4   = yb;

  // ---- CSR build ----
  hipMemsetAsync(cursor, 0, (size_t)N * 4, stream);
  int eblk = (EP + 255) / 256;
  k_count<<<eblk, 256, 0, stream>>>(ei, cursor, E, EP);
  k_scan<<<1, 256, 0, stream>>>(cursor, rowptr, N);
  k_fill<<<eblk, 256, 0, stream>>>(ei, cursor, srcn, E, EP);

  const int mfmaRows = (N + 127) / 128;     // 157
  const int tpRows   = (N + 63) / 64;       // 313
  const int nodeBlocks = (N + 3) / 4;

  // ---- text projection: fp32-A MFMA, BM=64 ----
  k_cvt_wt<<<dim3(2, TD / 32), 256, 0, stream>>>(tp_w, WtTP, TD, 64);
  k_gemm_tp<<<dim3(1, tpRows), 512, 0, stream>>>(x, WtTP, tp_b, h0h, N, TD);

  auto layer8 = [&](const unsigned short* actbf, int Kin, int l,
                    const unsigned short* resb, int catoff){
    k_cvt_wt2<<<dim3(32, Kin / 32), 256, 0, stream>>>(cw[l][0], cw[l][2], WtLR, Kin, 512);
    k_gemm_b64<<<dim3(4, mfmaRows), 512, 0, stream>>>(actbf, WtLR, cw[l][1], cw[l][3], 512,
                                                      xlrb, N, Kin, 1024);
    k_gat_fused8<<<nodeBlocks, 256, 0, stream>>>(xlrb, cw[l][4], rowptr, srcn,
                                                 cw[l][5], resb, yb, N);
    k_gnorm_stats<<<dim3(G, 8, NCHUNK), 256, 0, stream>>>(yb, ptrg, psum, psq, 512);
    k_gnorm_coef<<<G, 256, 0, stream>>>(psum, psq, nw[l][0], nw[l][1], nw[l][2], ptrg, cA, cC, 512);
    int total4 = N * 128;
    k_gnorm_apply<<<(total4 + 255) / 256, 256, 0, stream>>>(yb, batch, cA, cC, actA,
                                                            ptrg, cat, catoff, FD,
                                                            512, total4, 1);
  };

  layer8(h0h,  64,  0, nullptr, 0);
  layer8(actA, 512, 1, actA,    512);
  layer8(actA, 512, 2, actA,    1024);

  // ---- layer 4: combined xl|xr MFMA (Ncol=128) + fused edge + gnorm ----
  k_cvt_wt2<<<dim3(4, 16), 256, 0, stream>>>(cw[3][0], cw[3][2], Wt4, 512, 64);
  k_gemm_mfma8<128><<<dim3(1, mfmaRows), 512, 0, stream>>>(actA, Wt4, cw[3][1], cw[3][3], 64,
                                                           xlr4b, N, 512, 128);
  k_gat_fused1<<<nodeBlocks, 256, 0, stream>>>(xlr4b, cw[3][4], rowptr, srcn,
                                               cw[3][5], yb4, N);
  k_gnorm_stats<<<dim3(G, 1, NCHUNK), 256, 0, stream>>>(yb4, ptrg, psum, psq, 64);
  k_gnorm_coef<<<G, 256, 0, stream>>>(psum, psq, nw[3][0], nw[3][1], nw[3][2], ptrg, cA, cC, 64);
  k_gnorm_apply<<<(N * 16 + 255) / 256, 256, 0, stream>>>(yb4, batch, cA, cC, h0h,
                                                          ptrg, cat, 1536, FD,
                                                          64, N * 16, 0);

  k_final<<<G, 256, 0, stream>>>(cat, lin_w, lin_b, out, FD);
}

// Round 13
// 481.915 us; speedup vs baseline: 1.3709x; 1.3709x over previous
//
#include <hip/hip_runtime.h>
#include <hip/hip_bf16.h>

#define NEG_SLOPE 0.2f
#define EPSI 1e-5f
#define THR 8.0f

typedef __attribute__((ext_vector_type(8))) short bf16x8;
typedef __attribute__((ext_vector_type(4))) float f32x4;
typedef __attribute__((ext_vector_type(2))) float f32x2;

__device__ __forceinline__ float wred_sum(float v){
#pragma unroll
  for (int o = 32; o > 0; o >>= 1) v += __shfl_xor(v, o);
  return v;
}

__device__ __forceinline__ unsigned short f2bf(float f){
  __hip_bfloat16 h = __float2bfloat16(f);
  return *reinterpret_cast<unsigned short*>(&h);
}
__device__ __forceinline__ float bf2f(unsigned short u){
  return __uint_as_float((unsigned int)u << 16);
}
__device__ __forceinline__ f32x2 bfpair(unsigned int u){
  f32x2 r;
  r.x = __uint_as_float(u << 16);
  r.y = __uint_as_float(u & 0xffff0000u);
  return r;
}
__device__ __forceinline__ f32x2 vmax2(f32x2 a, f32x2 b){
#if __has_builtin(__builtin_elementwise_max)
  return __builtin_elementwise_max(a, b);
#else
  f32x2 r; r.x = fmaxf(a.x, b.x); r.y = fmaxf(a.y, b.y); return r;
#endif
}

__device__ __forceinline__ void gload16(const void* g, void* l){
  __builtin_amdgcn_global_load_lds((const __attribute__((address_space(1))) unsigned int*)g,
                                   (__attribute__((address_space(3))) unsigned int*)l, 16, 0, 0);
}

// ---------------- CSR build (by dst) ----------------
__global__ __launch_bounds__(256) void k_count(const int* __restrict__ ei, int* __restrict__ deg,
                                               int E, int EP){
  int e = blockIdx.x * 256 + threadIdx.x;
  if (e >= EP) return;
  int d = (e < E) ? ei[E + e] : (e - E);
  atomicAdd(&deg[d], 1);
}

__global__ __launch_bounds__(256) void k_scan(int* __restrict__ deg, int* __restrict__ rowptr, int n){
  __shared__ int part[256];
  int t = threadIdx.x;
  int L = (n + 255) / 256;
  int lo = t * L, hi = min(lo + L, n);
  int s = 0;
  for (int i = lo; i < hi; i++) s += deg[i];
  part[t] = s;
  __syncthreads();
  if (t == 0){
    int acc = 0;
    for (int i = 0; i < 256; i++){ int v = part[i]; part[i] = acc; acc += v; }
  }
  __syncthreads();
  int acc = part[t];
  for (int i = lo; i < hi; i++){
    int d = deg[i];
    rowptr[i] = acc;
    deg[i] = acc;
    acc += d;
  }
  if (t == 255) rowptr[n] = acc;
}

__global__ __launch_bounds__(256) void k_fill(const int* __restrict__ ei, int* __restrict__ cursor,
                                              int* __restrict__ srcn, int E, int EP){
  int e = blockIdx.x * 256 + threadIdx.x;
  if (e >= EP) return;
  int s, d;
  if (e < E){ s = ei[e]; d = ei[E + e]; } else { s = d = e - E; }
  int pos = atomicAdd(&cursor[d], 1);
  srcn[pos] = s;
}

// ---------------- bf16 weight transposes ----------------
__global__ __launch_bounds__(256) void k_cvt_wt(const float* __restrict__ W,
                                                unsigned short* __restrict__ Wt,
                                                int K, int Ncol){
  __shared__ float t[32][33];
  int bx = blockIdx.x, by = blockIdx.y;
  int tx = threadIdx.x & 31, ty = threadIdx.x >> 5;
#pragma unroll
  for (int i = 0; i < 4; i++)
    t[ty + i * 8][tx] = W[(size_t)(by * 32 + ty + i * 8) * Ncol + bx * 32 + tx];
  __syncthreads();
#pragma unroll
  for (int i = 0; i < 4; i++)
    Wt[(size_t)(bx * 32 + ty + i * 8) * K + by * 32 + tx] = f2bf(t[tx][ty + i * 8]);
}

__global__ __launch_bounds__(256) void k_cvt_wt2(const float* __restrict__ Wa,
                                                 const float* __restrict__ Wb,
                                                 unsigned short* __restrict__ Wt,
                                                 int K, int Ncol){
  __shared__ float t[32][33];
  int half = gridDim.x >> 1;
  int isB = blockIdx.x >= half;
  const float* W = isB ? Wb : Wa;
  unsigned short* out = Wt + (isB ? (size_t)Ncol * K : 0);
  int bx = isB ? blockIdx.x - half : blockIdx.x;
  int by = blockIdx.y;
  int tx = threadIdx.x & 31, ty = threadIdx.x >> 5;
#pragma unroll
  for (int i = 0; i < 4; i++)
    t[ty + i * 8][tx] = W[(size_t)(by * 32 + ty + i * 8) * Ncol + bx * 32 + tx];
  __syncthreads();
#pragma unroll
  for (int i = 0; i < 4; i++)
    out[(size_t)(bx * 32 + ty + i * 8) * K + by * 32 + tx] = f2bf(t[tx][ty + i * 8]);
}

// ---------------- bf16 MFMA GEMM, BK=64 2-phase, 128x256 tile, 8 waves ----------------
__global__ __launch_bounds__(512) void k_gemm_b64(const unsigned short* __restrict__ A,
                                                  const unsigned short* __restrict__ Wt,
                                                  const float* __restrict__ ba,
                                                  const float* __restrict__ bb,
                                                  int bsplit,
                                                  unsigned short* __restrict__ Cb,
                                                  int M, int K, int Ncol){
  __shared__ unsigned short As[128 * 64];
  __shared__ unsigned short Bs[256 * 64];
  const int tid = threadIdx.x;
  const int w = tid >> 6, lane = tid & 63;
  const int wr = w >> 2, wc = w & 3;
  const int row0 = blockIdx.y * 128, col0 = blockIdx.x * 256;
  const int lr = lane & 15, lk = lane >> 4;

  f32x4 acc[4][4];
#pragma unroll
  for (int i = 0; i < 4; i++)
#pragma unroll
    for (int j = 0; j < 4; j++) acc[i][j] = (f32x4){0.f, 0.f, 0.f, 0.f};

  for (int k0 = 0; k0 < K; k0 += 64){
#pragma unroll
    for (int t = 0; t < 2; t++){
      int g = w * 64 + lane + t * 512;
      int row = g >> 3, slot = g & 7;
      int kq = slot ^ ((row >> 1) & 7);
      int srow = row0 + row; if (srow >= M) srow = M - 1;
      gload16(&A[(size_t)srow * K + k0 + kq * 8], &As[(size_t)(w * 64 + t * 512) * 8]);
    }
#pragma unroll
    for (int t = 0; t < 4; t++){
      int g = w * 64 + lane + t * 512;
      int col = g >> 3, slot = g & 7;
      int kq = slot ^ ((col >> 1) & 7);
      gload16(&Wt[(size_t)(col0 + col) * K + k0 + kq * 8], &Bs[(size_t)(w * 64 + t * 512) * 8]);
    }
    __syncthreads();

#pragma unroll
    for (int ph = 0; ph < 2; ph++){
      bf16x8 af[4], bf_[4];
#pragma unroll
      for (int mi = 0; mi < 4; mi++){
        int rl = wr * 64 + mi * 16 + lr;
        int sl = (ph * 4 + lk) ^ ((rl >> 1) & 7);
        af[mi] = *(const bf16x8*)&As[(rl * 8 + sl) * 8];
      }
#pragma unroll
      for (int ni = 0; ni < 4; ni++){
        int cl = wc * 64 + ni * 16 + lr;
        int sl = (ph * 4 + lk) ^ ((cl >> 1) & 7);
        bf_[ni] = *(const bf16x8*)&Bs[(cl * 8 + sl) * 8];
      }
#pragma unroll
      for (int mi = 0; mi < 4; mi++)
#pragma unroll
        for (int ni = 0; ni < 4; ni++)
          acc[mi][ni] = __builtin_amdgcn_mfma_f32_16x16x32_bf16(af[mi], bf_[ni], acc[mi][ni], 0, 0, 0);
    }
    __syncthreads();
  }

#pragma unroll
  for (int mi = 0; mi < 4; mi++){
#pragma unroll
    for (int ni = 0; ni < 4; ni++){
      int gc = col0 + wc * 64 + ni * 16 + lr;
      float bv = gc < bsplit ? ba[gc] : bb[gc - bsplit];
#pragma unroll
      for (int r = 0; r < 4; r++){
        int gr = row0 + wr * 64 + mi * 16 + lk * 4 + r;
        if (gr < M) Cb[(size_t)gr * Ncol + gc] = f2bf(acc[mi][ni][r] + bv);
      }
    }
  }
}

// ---------------- bf16 MFMA GEMM, 8 waves, 128 x BN tile, BK=32 (L4) ----------------
template<int BN>
__global__ __launch_bounds__(512) void k_gemm_mfma8(const unsigned short* __restrict__ A,
                                                    const unsigned short* __restrict__ Wt,
                                                    const float* __restrict__ ba,
                                                    const float* __restrict__ bb,
                                                    int bsplit,
                                                    unsigned short* __restrict__ Cb,
                                                    int M, int K, int Ncol){
  constexpr int NF = BN / 64;
  __shared__ unsigned short As[128 * 32];
  __shared__ unsigned short Bs[BN * 32];
  const int tid = threadIdx.x;
  const int w = tid >> 6, lane = tid & 63;
  const int wr = w >> 2, wc = w & 3;
  const int row0 = blockIdx.y * 128, col0 = blockIdx.x * BN;
  const int lr = lane & 15, lk = lane >> 4;
  const int swz = (lr >> 1) & 3;

  f32x4 acc[4][NF];
#pragma unroll
  for (int i = 0; i < 4; i++)
#pragma unroll
    for (int j = 0; j < NF; j++) acc[i][j] = (f32x4){0.f, 0.f, 0.f, 0.f};

  for (int k0 = 0; k0 < K; k0 += 32){
    for (int g0 = w * 64; g0 < 512; g0 += 512){
      int g = g0 + lane;
      int row = g >> 2, slot = g & 3;
      int kq = slot ^ ((row >> 1) & 3);
      int srow = row0 + row; if (srow >= M) srow = M - 1;
      gload16(&A[(size_t)srow * K + k0 + kq * 8], &As[(size_t)g0 * 8]);
    }
    for (int g0 = w * 64; g0 < BN * 4; g0 += 512){
      int g = g0 + lane;
      int col = g >> 2, slot = g & 3;
      int kq = slot ^ ((col >> 1) & 3);
      gload16(&Wt[(size_t)(col0 + col) * K + k0 + kq * 8], &Bs[(size_t)g0 * 8]);
    }
    __syncthreads();

    bf16x8 af[4], bf_[NF];
#pragma unroll
    for (int mi = 0; mi < 4; mi++){
      int rl = wr * 64 + mi * 16 + lr;
      af[mi] = *(const bf16x8*)&As[(rl * 4 + (lk ^ swz)) * 8];
    }
#pragma unroll
    for (int ni = 0; ni < NF; ni++){
      int cl = wc * (BN / 4) + ni * 16 + lr;
      bf_[ni] = *(const bf16x8*)&Bs[(cl * 4 + (lk ^ swz)) * 8];
    }
#pragma unroll
    for (int mi = 0; mi < 4; mi++)
#pragma unroll
      for (int ni = 0; ni < NF; ni++)
        acc[mi][ni] = __builtin_amdgcn_mfma_f32_16x16x32_bf16(af[mi], bf_[ni], acc[mi][ni], 0, 0, 0);
    __syncthreads();
  }

#pragma unroll
  for (int mi = 0; mi < 4; mi++){
#pragma unroll
    for (int ni = 0; ni < NF; ni++){
      int gc = col0 + wc * (BN / 4) + ni * 16 + lr;
      float bv = gc < bsplit ? ba[gc] : bb[gc - bsplit];
#pragma unroll
      for (int r = 0; r < 4; r++){
        int gr = row0 + wr * 64 + mi * 16 + lk * 4 + r;
        if (gr < M) Cb[(size_t)gr * Ncol + gc] = f2bf(acc[mi][ni][r] + bv);
      }
    }
  }
}

// ---------------- text-proj GEMM: fp32 A reg-staged -> bf16 LDS; BM=64, Ncol=64 ----------------
__global__ __launch_bounds__(512) void k_gemm_tp(const float* __restrict__ A,
                                                 const unsigned short* __restrict__ Wt,
                                                 const float* __restrict__ bias,
                                                 unsigned short* __restrict__ Cb,
                                                 int M, int K){
  __shared__ unsigned short As[64 * 32];
  __shared__ unsigned short Bs[64 * 32];
  const int tid = threadIdx.x;
  const int w = tid >> 6, lane = tid & 63;
  const int wr = w >> 2, wc = w & 3;
  const int row0 = blockIdx.y * 64;
  const int lr = lane & 15, lk = lane >> 4;
  const int swz = (lr >> 1) & 3;

  f32x4 acc[2];
  acc[0] = (f32x4){0.f, 0.f, 0.f, 0.f};
  acc[1] = (f32x4){0.f, 0.f, 0.f, 0.f};

  for (int k0 = 0; k0 < K; k0 += 32){
    if (tid < 256){
      int g = tid;
      int row = g >> 2, slot = g & 3;
      int kq = slot ^ ((row >> 1) & 3);
      int srow = row0 + row; if (srow >= M) srow = M - 1;
      const float* ap = &A[(size_t)srow * K + k0 + kq * 8];
      float4 f0 = *(const float4*)ap;
      float4 f1 = *(const float4*)(ap + 4);
      bf16x8 v;
      v[0] = (short)f2bf(f0.x); v[1] = (short)f2bf(f0.y);
      v[2] = (short)f2bf(f0.z); v[3] = (short)f2bf(f0.w);
      v[4] = (short)f2bf(f1.x); v[5] = (short)f2bf(f1.y);
      v[6] = (short)f2bf(f1.z); v[7] = (short)f2bf(f1.w);
      *(bf16x8*)&As[(size_t)g * 8] = v;
    } else {
      int g = tid - 256;
      int col = g >> 2, slot = g & 3;
      int kq = slot ^ ((col >> 1) & 3);
      gload16(&Wt[(size_t)col * K + k0 + kq * 8], &Bs[(size_t)g * 8]);
    }
    __syncthreads();

    bf16x8 af[2], bfr;
#pragma unroll
    for (int mi = 0; mi < 2; mi++){
      int rl = wr * 32 + mi * 16 + lr;
      af[mi] = *(const bf16x8*)&As[(rl * 4 + (lk ^ swz)) * 8];
    }
    {
      int cl = wc * 16 + lr;
      bfr = *(const bf16x8*)&Bs[(cl * 4 + (lk ^ swz)) * 8];
    }
    acc[0] = __builtin_amdgcn_mfma_f32_16x16x32_bf16(af[0], bfr, acc[0], 0, 0, 0);
    acc[1] = __builtin_amdgcn_mfma_f32_16x16x32_bf16(af[1], bfr, acc[1], 0, 0, 0);
    __syncthreads();
  }

  int gc = wc * 16 + lr;
  float bv = bias[gc];
#pragma unroll
  for (int mi = 0; mi < 2; mi++)
#pragma unroll
    for (int r = 0; r < 4; r++){
      int gr = row0 + wr * 32 + mi * 16 + lk * 4 + r;
      if (gr < M) Cb[(size_t)gr * 64 + gc] = f2bf(acc[mi][r] + bv);
    }
}

// ---------------- fused GATv2 edge phase, 8 heads (single-wave, dual-state, defer-max) ----------------
// NOTE: plain launch_bounds(256). R12's (256,8) forced 48->32 VGPR => scratch spills (2.2x slower).
__global__ __launch_bounds__(256) void k_gat_fused8(const unsigned short* __restrict__ xlrb,
                                                    const float* __restrict__ att,
                                                    const int* __restrict__ rowptr,
                                                    const int* __restrict__ srcn,
                                                    const float* __restrict__ bias,
                                                    const unsigned short* __restrict__ resb,
                                                    unsigned short* __restrict__ yb,
                                                    int N){
  int node = (blockIdx.x * 256 + threadIdx.x) >> 6;
  int lane = threadIdx.x & 63;
  if (node >= N) return;
  f32x2 xr2[4], av2[4];
  {
    uint4 ur = *(const uint4*)&xlrb[(size_t)node * 1024 + 512 + lane * 8];
    xr2[0] = bfpair(ur.x); xr2[1] = bfpair(ur.y); xr2[2] = bfpair(ur.z); xr2[3] = bfpair(ur.w);
    float4 a0 = *(const float4*)&att[lane * 8];
    float4 a1 = *(const float4*)&att[lane * 8 + 4];
    av2[0] = (f32x2){a0.x, a0.y}; av2[1] = (f32x2){a0.z, a0.w};
    av2[2] = (f32x2){a1.x, a1.y}; av2[3] = (f32x2){a1.z, a1.w};
  }
  int e0 = rowptr[node], e1 = rowptr[node + 1];
  float m0 = -1e30f, s0 = 0.f, m1 = -1e30f, s1 = 0.f;
  f32x2 acc0[4] = {}, acc1[4] = {};

  for (int base = e0; base < e1; base += 64){
    int cnt = min(64, e1 - base);
    int sn = 0;
    if (lane < cnt) sn = srcn[base + lane];
    int k = 0;
    for (; k + 1 < cnt; k += 2){
      int ska = __shfl(sn, k);
      int skb = __shfl(sn, k + 1);
      uint4 ua = *(const uint4*)&xlrb[(size_t)ska * 1024 + lane * 8];
      uint4 ub = *(const uint4*)&xlrb[(size_t)skb * 1024 + lane * 8];
      f32x2 va[4], vb[4];
      va[0] = bfpair(ua.x); va[1] = bfpair(ua.y); va[2] = bfpair(ua.z); va[3] = bfpair(ua.w);
      vb[0] = bfpair(ub.x); vb[1] = bfpair(ub.y); vb[2] = bfpair(ub.z); vb[3] = bfpair(ub.w);
      f32x2 da = (f32x2){0.f, 0.f}, db = (f32x2){0.f, 0.f};
#pragma unroll
      for (int j = 0; j < 4; j++){
        f32x2 ta = va[j] + xr2[j];
        f32x2 tb = vb[j] + xr2[j];
        ta = vmax2(ta, ta * NEG_SLOPE);
        tb = vmax2(tb, tb * NEG_SLOPE);
        da += ta * av2[j];
        db += tb * av2[j];
      }
      float suma = da.x + da.y, sumb = db.x + db.y;
      suma += __shfl_xor(suma, 1); sumb += __shfl_xor(sumb, 1);
      suma += __shfl_xor(suma, 2); sumb += __shfl_xor(sumb, 2);
      suma += __shfl_xor(suma, 4); sumb += __shfl_xor(sumb, 4);
      if (__builtin_expect(__any(suma > m0 + THR), 0)){
        float mn = fmaxf(m0, suma);
        float cs = __expf(m0 - mn);
        float p  = __expf(suma - mn);
        s0 = s0 * cs + p;
#pragma unroll
        for (int j = 0; j < 4; j++) acc0[j] = acc0[j] * cs + va[j] * p;
        m0 = mn;
      } else {
        float p = __expf(suma - m0);
        s0 += p;
#pragma unroll
        for (int j = 0; j < 4; j++) acc0[j] += va[j] * p;
      }
      if (__builtin_expect(__any(sumb > m1 + THR), 0)){
        float mn = fmaxf(m1, sumb);
        float cs = __expf(m1 - mn);
        float p  = __expf(sumb - mn);
        s1 = s1 * cs + p;
#pragma unroll
        for (int j = 0; j < 4; j++) acc1[j] = acc1[j] * cs + vb[j] * p;
        m1 = mn;
      } else {
        float p = __expf(sumb - m1);
        s1 += p;
#pragma unroll
        for (int j = 0; j < 4; j++) acc1[j] += vb[j] * p;
      }
    }
    if (k < cnt){
      int ska = __shfl(sn, k);
      uint4 ua = *(const uint4*)&xlrb[(size_t)ska * 1024 + lane * 8];
      f32x2 va[4];
      va[0] = bfpair(ua.x); va[1] = bfpair(ua.y); va[2] = bfpair(ua.z); va[3] = bfpair(ua.w);
      f32x2 da = (f32x2){0.f, 0.f};
#pragma unroll
      for (int j = 0; j < 4; j++){
        f32x2 ta = va[j] + xr2[j];
        ta = vmax2(ta, ta * NEG_SLOPE);
        da += ta * av2[j];
      }
      float suma = da.x + da.y;
      suma += __shfl_xor(suma, 1);
      suma += __shfl_xor(suma, 2);
      suma += __shfl_xor(suma, 4);
      if (__builtin_expect(__any(suma > m0 + THR), 0)){
        float mn = fmaxf(m0, suma);
        float cs = __expf(m0 - mn);
        float p  = __expf(suma - mn);
        s0 = s0 * cs + p;
#pragma unroll
        for (int j = 0; j < 4; j++) acc0[j] = acc0[j] * cs + va[j] * p;
        m0 = mn;
      } else {
        float p = __expf(suma - m0);
        s0 += p;
#pragma unroll
        for (int j = 0; j < 4; j++) acc0[j] += va[j] * p;
      }
    }
  }
  float m = fmaxf(m0, m1);
  float c0 = __expf(m0 - m), c1 = __expf(m1 - m);
  float s = s0 * c0 + s1 * c1;
  float inv = 1.f / s;
  float4 b0 = *(const float4*)&bias[lane * 8];
  float4 b1 = *(const float4*)&bias[lane * 8 + 4];
  f32x2 bi2[4] = {(f32x2){b0.x, b0.y}, (f32x2){b0.z, b0.w},
                  (f32x2){b1.x, b1.y}, (f32x2){b1.z, b1.w}};
  f32x2 re2[4] = {};
  size_t o = (size_t)node * 512 + lane * 8;
  if (resb){
    uint4 rr = *(const uint4*)&resb[o];
    re2[0] = bfpair(rr.x); re2[1] = bfpair(rr.y); re2[2] = bfpair(rr.z); re2[3] = bfpair(rr.w);
  }
  bf16x8 ov;
#pragma unroll
  for (int j = 0; j < 4; j++){
    f32x2 r = (acc0[j] * c0 + acc1[j] * c1) * inv + bi2[j] + re2[j];
    ov[2 * j]     = (short)f2bf(r.x);
    ov[2 * j + 1] = (short)f2bf(r.y);
  }
  *(bf16x8*)&yb[o] = ov;
}

// ---------------- fused GATv2 edge phase, 1 head, OD=64 (layer 4, quad-state) ----------------
__global__ __launch_bounds__(256) void k_gat_fused1(const unsigned short* __restrict__ xlr,
                                                    const float* __restrict__ att,
                                                    const int* __restrict__ rowptr,
                                                    const int* __restrict__ srcn,
                                                    const float* __restrict__ bias,
                                                    unsigned short* __restrict__ yb4,
                                                    int N){
  int node = (blockIdx.x * 256 + threadIdx.x) >> 6;
  int lane = threadIdx.x & 63;
  if (node >= N) return;
  float xrv = bf2f(xlr[(size_t)node * 128 + 64 + lane]);
  float attv = att[lane];
  int e0 = rowptr[node], e1 = rowptr[node + 1];
  float m[4] = {-1e30f, -1e30f, -1e30f, -1e30f};
  float s[4] = {0.f, 0.f, 0.f, 0.f};
  float acc[4] = {0.f, 0.f, 0.f, 0.f};
  for (int base = e0; base < e1; base += 64){
    int cnt = min(64, e1 - base);
    int sn = 0;
    if (lane < cnt) sn = srcn[base + lane];
    for (int k = 0; k < cnt; k += 4){
#pragma unroll
      for (int j = 0; j < 4; j++){
        if (k + j < cnt){
          int sk = __shfl(sn, k + j);
          float v = bf2f(xlr[(size_t)sk * 128 + lane]);
          float t = v + xrv;
          t = fmaxf(t, t * NEG_SLOPE);
          float sum = wred_sum(t * attv);
          if (sum > m[j] + THR){
            float mn = fmaxf(m[j], sum);
            float cs = __expf(m[j] - mn);
            float p  = __expf(sum - mn);
            s[j] = s[j] * cs + p;
            acc[j] = acc[j] * cs + p * v;
            m[j] = mn;
          } else {
            float p = __expf(sum - m[j]);
            s[j] += p;
            acc[j] += p * v;
          }
        }
      }
    }
  }
  float mm = fmaxf(fmaxf(m[0], m[1]), fmaxf(m[2], m[3]));
  float st = 0.f, at = 0.f;
#pragma unroll
  for (int j = 0; j < 4; j++){
    float c = __expf(m[j] - mm);
    st += s[j] * c;
    at += acc[j] * c;
  }
  yb4[(size_t)node * 64 + lane] = f2bf(at / st + bias[lane]);
}

// ---------------- GraphNorm: chunked stats (bf16 in) -> coef -> apply (bf16 in/out + cat) ----------------
#define NCHUNK 16
__global__ __launch_bounds__(256) void k_gnorm_stats(const unsigned short* __restrict__ y,
                                                     const int* __restrict__ ptrg,
                                                     float* __restrict__ psum,
                                                     float* __restrict__ psq,
                                                     int OD){
  int g = blockIdx.x, chunk = blockIdx.z;
  int lane = threadIdx.x & 63, sub = threadIdx.x >> 6;
  int c = blockIdx.y * 64 + lane;
  int lo = ptrg[g], hi = ptrg[g + 1], len = hi - lo;
  int c0 = lo + (len * chunk) / NCHUNK, c1 = lo + (len * (chunk + 1)) / NCHUNK;
  float s = 0.f, q = 0.f;
  for (int i = c0 + sub; i < c1; i += 4){
    float v = bf2f(y[(size_t)i * OD + c]);
    s += v; q += v * v;
  }
  __shared__ float sm[4][64], sq2[4][64];
  sm[sub][lane] = s; sq2[sub][lane] = q;
  __syncthreads();
  if (sub == 0){
    s = sm[0][lane] + sm[1][lane] + sm[2][lane] + sm[3][lane];
    q = sq2[0][lane] + sq2[1][lane] + sq2[2][lane] + sq2[3][lane];
    size_t o = (size_t)(g * NCHUNK + chunk) * OD + c;
    psum[o] = s; psq[o] = q;
  }
}

__global__ __launch_bounds__(256) void k_gnorm_coef(const float* __restrict__ psum,
                                                    const float* __restrict__ psq,
                                                    const float* __restrict__ w,
                                                    const float* __restrict__ b,
                                                    const float* __restrict__ ms,
                                                    const int* __restrict__ ptrg,
                                                    float* __restrict__ cA,
                                                    float* __restrict__ cC,
                                                    int OD){
  int g = blockIdx.x;
  int len = ptrg[g + 1] - ptrg[g];
  float inv_n = 1.f / (float)len;
  for (int c = threadIdx.x; c < OD; c += 256){
    float s = 0.f, q = 0.f;
    for (int k = 0; k < NCHUNK; k++){
      size_t o = (size_t)(g * NCHUNK + k) * OD + c;
      s += psum[o]; q += psq[o];
    }
    float mean = s * inv_n, ey2 = q * inv_n;
    float m = ms[c];
    float var = ey2 - mean * mean * (2.f * m - m * m);
    float inv = rsqrtf(var + EPSI);
    float A = w[c] * inv;
    cA[(size_t)g * OD + c] = A;
    cC[(size_t)g * OD + c] = b[c] - A * m * mean;
  }
}

__global__ __launch_bounds__(256) void k_gnorm_apply(const unsigned short* __restrict__ y,
                                                     const int* __restrict__ batch,
                                                     const float* __restrict__ cA,
                                                     const float* __restrict__ cC,
                                                     unsigned short* __restrict__ outb,
                                                     const int* __restrict__ ptrg,
                                                     float* __restrict__ cat,
                                                     int catoff, int FD,
                                                     int OD, int total4, int do_elu){
  int idx = blockIdx.x * 256 + threadIdx.x;
  if (idx >= total4) return;
  int od4 = OD >> 2;
  int node = idx / od4;
  int c = (idx - node * od4) << 2;
  int g = batch[node];
  ushort4 uv = ((const ushort4*)y)[idx];
  float4 v = make_float4(bf2f(uv.x), bf2f(uv.y), bf2f(uv.z), bf2f(uv.w));
  float4 A = *(const float4*)&cA[(size_t)g * OD + c];
  float4 Cc = *(const float4*)&cC[(size_t)g * OD + c];
  float4 r;
  r.x = A.x * v.x + Cc.x;
  r.y = A.y * v.y + Cc.y;
  r.z = A.z * v.z + Cc.z;
  r.w = A.w * v.w + Cc.w;
  if (do_elu){
    r.x = r.x > 0.f ? r.x : expf(r.x) - 1.f;
    r.y = r.y > 0.f ? r.y : expf(r.y) - 1.f;
    r.z = r.z > 0.f ? r.z : expf(r.z) - 1.f;
    r.w = r.w > 0.f ? r.w : expf(r.w) - 1.f;
  }
  ushort4 ob;
  ob.x = f2bf(r.x); ob.y = f2bf(r.y); ob.z = f2bf(r.z); ob.w = f2bf(r.w);
  ((ushort4*)outb)[idx] = ob;
  if (node == ptrg[g])
    *(float4*)&cat[(size_t)g * FD + catoff + c] = r;
}

// ---------------- final linear on 50 summary rows ----------------
__global__ __launch_bounds__(256) void k_final(const float* __restrict__ cat,
                                               const float* __restrict__ lin_w,
                                               const float* __restrict__ lin_b,
                                               float* __restrict__ out, int FD){
  int g = blockIdx.x;
  float s = 0.f;
  for (int c = threadIdx.x; c < FD; c += 256) s += cat[(size_t)g * FD + c] * lin_w[c];
  s = wred_sum(s);
  __shared__ float sm[4];
  if ((threadIdx.x & 63) == 0) sm[threadIdx.x >> 6] = s;
  __syncthreads();
  if (threadIdx.x == 0) out[g] = sm[0] + sm[1] + sm[2] + sm[3] + lin_b[0];
}

extern "C" void kernel_launch(void* const* d_in, const int* in_sizes, int n_in,
                              void* d_out, int out_size, void* d_ws, size_t ws_size,
                              hipStream_t stream) {
  const int TD = 768, HC = 64, H = 8;
  const float* x     = (const float*)d_in[0];
  const int*   ei    = (const int*)d_in[1];
  const int*   batch = (const int*)d_in[2];
  const int*   ptrg  = (const int*)d_in[3];
  const float* tp_w  = (const float*)d_in[4];
  const float* tp_b  = (const float*)d_in[5];
  const float* lin_w = (const float*)d_in[6];
  const float* lin_b = (const float*)d_in[7];
  const float* cw[4][6];
  for (int l = 0; l < 4; l++)
    for (int j = 0; j < 6; j++) cw[l][j] = (const float*)d_in[8 + 6 * l + j];
  const float* nw[4][3];
  for (int l = 0; l < 4; l++)
    for (int j = 0; j < 3; j++) nw[l][j] = (const float*)d_in[32 + 3 * l + j];

  const int N  = in_sizes[0] / TD;   // 20000
  const int E  = in_sizes[1] / 2;    // 240000
  const int EP = E + N;              // 260000
  const int G  = in_sizes[3] - 1;    // 50
  const int FD = 3 * HC * H + HC;    // 1600

  char* wsp = (char*)d_ws;
  size_t off = 0;
  auto alloc = [&](size_t b) -> void* {
    void* p = wsp + off;
    off += (b + 255) & ~(size_t)255;
    return p;
  };
  unsigned short* xlrb = (unsigned short*)alloc((size_t)N * 1024 * 2);
  unsigned short* yb   = (unsigned short*)alloc((size_t)N * 512 * 2);
  unsigned short* actA = (unsigned short*)alloc((size_t)N * 512 * 2);
  unsigned short* h0h  = (unsigned short*)alloc((size_t)N * 64 * 2);
  int*   rowptr= (int*)alloc((size_t)(N + 1) * 4);
  int*   cursor= (int*)alloc((size_t)N * 4);
  int*   srcn  = (int*)alloc((size_t)EP * 4);
  float* cat   = (float*)alloc((size_t)G * FD * 4);
  float* psum  = (float*)alloc((size_t)G * NCHUNK * 512 * 4);
  float* psq   = (float*)alloc((size_t)G * NCHUNK * 512 * 4);
  float* cA    = (float*)alloc((size_t)G * 512 * 4);
  float* cC    = (float*)alloc((size_t)G * 512 * 4);
  unsigned short* WtLR = (unsigned short*)alloc((size_t)1024 * 512 * 2);
  unsigned short* WtTP = (unsigned short*)alloc((size_t)64 * 768 * 2);
  unsigned short* Wt4  = (unsigned short*)alloc((size_t)128 * 512 * 2);
  (void)ws_size; (void)n_in; (void)out_size;

  float* out = (float*)d_out;

  unsigned short* xlr4b = xlrb;
  unsigned short* yb4   = yb;

  // ---- CSR build ----
  hipMemsetAsync(cursor, 0, (size_t)N * 4, stream);
  int eblk = (EP + 255) / 256;
  k_count<<<eblk, 256, 0, stream>>>(ei, cursor, E, EP);
  k_scan<<<1, 256, 0, stream>>>(cursor, rowptr, N);
  k_fill<<<eblk, 256, 0, stream>>>(ei, cursor, srcn, E, EP);

  const int mfmaRows = (N + 127) / 128;     // 157
  const int tpRows   = (N + 63) / 64;       // 313
  const int nodeBlocks = (N + 3) / 4;

  // ---- text projection: fp32-A MFMA, BM=64 ----
  k_cvt_wt<<<dim3(2, TD / 32), 256, 0, stream>>>(tp_w, WtTP, TD, 64);
  k_gemm_tp<<<dim3(1, tpRows), 512, 0, stream>>>(x, WtTP, tp_b, h0h, N, TD);

  auto layer8 = [&](const unsigned short* actbf, int Kin, int l,
                    const unsigned short* resb, int catoff){
    k_cvt_wt2<<<dim3(32, Kin / 32), 256, 0, stream>>>(cw[l][0], cw[l][2], WtLR, Kin, 512);
    k_gemm_b64<<<dim3(4, mfmaRows), 512, 0, stream>>>(actbf, WtLR, cw[l][1], cw[l][3], 512,
                                                      xlrb, N, Kin, 1024);
    k_gat_fused8<<<nodeBlocks, 256, 0, stream>>>(xlrb, cw[l][4], rowptr, srcn,
                                                 cw[l][5], resb, yb, N);
    k_gnorm_stats<<<dim3(G, 8, NCHUNK), 256, 0, stream>>>(yb, ptrg, psum, psq, 512);
    k_gnorm_coef<<<G, 256, 0, stream>>>(psum, psq, nw[l][0], nw[l][1], nw[l][2], ptrg, cA, cC, 512);
    int total4 = N * 128;
    k_gnorm_apply<<<(total4 + 255) / 256, 256, 0, stream>>>(yb, batch, cA, cC, actA,
                                                            ptrg, cat, catoff, FD,
                                                            512, total4, 1);
  };

  layer8(h0h,  64,  0, nullptr, 0);
  layer8(actA, 512, 1, actA,    512);
  layer8(actA, 512, 2, actA,    1024);

  // ---- layer 4: combined xl|xr MFMA (Ncol=128) + fused edge + gnorm ----
  k_cvt_wt2<<<dim3(4, 16), 256, 0, stream>>>(cw[3][0], cw[3][2], Wt4, 512, 64);
  k_gemm_mfma8<128><<<dim3(1, mfmaRows), 512, 0, stream>>>(actA, Wt4, cw[3][1], cw[3][3], 64,
                                                           xlr4b, N, 512, 128);
  k_gat_fused1<<<nodeBlocks, 256, 0, stream>>>(xlr4b, cw[3][4], rowptr, srcn,
                                               cw[3][5], yb4, N);
  k_gnorm_stats<<<dim3(G, 1, NCHUNK), 256, 0, stream>>>(yb4, ptrg, psum, psq, 64);
  k_gnorm_coef<<<G, 256, 0, stream>>>(psum, psq, nw[3][0], nw[3][1], nw[3][2], ptrg, cA, cC, 64);
  k_gnorm_apply<<<(N * 16 + 255) / 256, 256, 0, stream>>>(yb4, batch, cA, cC, h0h,
                                                          ptrg, cat, 1536, FD,
                                                          64, N * 16, 0);

  k_final<<<G, 256, 0, stream>>>(cat, lin_w, lin_b, out, FD);
}

// Round 15
// 478.966 us; speedup vs baseline: 1.3793x; 1.0062x over previous
//
#include <hip/hip_runtime.h>
#include <hip/hip_bf16.h>

#define NEG_SLOPE 0.2f
#define EPSI 1e-5f
#define THR 8.0f

typedef __attribute__((ext_vector_type(8))) short bf16x8;
typedef __attribute__((ext_vector_type(4))) float f32x4;
typedef __attribute__((ext_vector_type(2))) float f32x2;

__device__ __forceinline__ float wred_sum(float v){
#pragma unroll
  for (int o = 32; o > 0; o >>= 1) v += __shfl_xor(v, o);
  return v;
}

__device__ __forceinline__ unsigned short f2bf(float f){
  __hip_bfloat16 h = __float2bfloat16(f);
  return *reinterpret_cast<unsigned short*>(&h);
}
__device__ __forceinline__ float bf2f(unsigned short u){
  return __uint_as_float((unsigned int)u << 16);
}
__device__ __forceinline__ f32x2 bfpair(unsigned int u){
  f32x2 r;
  r.x = __uint_as_float(u << 16);
  r.y = __uint_as_float(u & 0xffff0000u);
  return r;
}
__device__ __forceinline__ f32x2 vmax2(f32x2 a, f32x2 b){
#if __has_builtin(__builtin_elementwise_max)
  return __builtin_elementwise_max(a, b);
#else
  f32x2 r; r.x = fmaxf(a.x, b.x); r.y = fmaxf(a.y, b.y); return r;
#endif
}

__device__ __forceinline__ void gload16(const void* g, void* l){
  __builtin_amdgcn_global_load_lds((const __attribute__((address_space(1))) unsigned int*)g,
                                   (__attribute__((address_space(3))) unsigned int*)l, 16, 0, 0);
}

// ---------------- CSR build (by dst) ----------------
__global__ __launch_bounds__(256) void k_count(const int* __restrict__ ei, int* __restrict__ deg,
                                               int E, int EP){
  int e = blockIdx.x * 256 + threadIdx.x;
  if (e >= EP) return;
  int d = (e < E) ? ei[E + e] : (e - E);
  atomicAdd(&deg[d], 1);
}

__global__ __launch_bounds__(256) void k_scan(int* __restrict__ deg, int* __restrict__ rowptr, int n){
  __shared__ int part[256];
  int t = threadIdx.x;
  int L = (n + 255) / 256;
  int lo = t * L, hi = min(lo + L, n);
  int s = 0;
  for (int i = lo; i < hi; i++) s += deg[i];
  part[t] = s;
  __syncthreads();
  if (t == 0){
    int acc = 0;
    for (int i = 0; i < 256; i++){ int v = part[i]; part[i] = acc; acc += v; }
  }
  __syncthreads();
  int acc = part[t];
  for (int i = lo; i < hi; i++){
    int d = deg[i];
    rowptr[i] = acc;
    deg[i] = acc;
    acc += d;
  }
  if (t == 255) rowptr[n] = acc;
}

__global__ __launch_bounds__(256) void k_fill(const int* __restrict__ ei, int* __restrict__ cursor,
                                              int* __restrict__ srcn, int E, int EP){
  int e = blockIdx.x * 256 + threadIdx.x;
  if (e >= EP) return;
  int s, d;
  if (e < E){ s = ei[e]; d = ei[E + e]; } else { s = d = e - E; }
  int pos = atomicAdd(&cursor[d], 1);
  srcn[pos] = s;
}

// ---------------- bf16 weight transposes ----------------
__global__ __launch_bounds__(256) void k_cvt_wt(const float* __restrict__ W,
                                                unsigned short* __restrict__ Wt,
                                                int K, int Ncol){
  __shared__ float t[32][33];
  int bx = blockIdx.x, by = blockIdx.y;
  int tx = threadIdx.x & 31, ty = threadIdx.x >> 5;
#pragma unroll
  for (int i = 0; i < 4; i++)
    t[ty + i * 8][tx] = W[(size_t)(by * 32 + ty + i * 8) * Ncol + bx * 32 + tx];
  __syncthreads();
#pragma unroll
  for (int i = 0; i < 4; i++)
    Wt[(size_t)(bx * 32 + ty + i * 8) * K + by * 32 + tx] = f2bf(t[tx][ty + i * 8]);
}

__global__ __launch_bounds__(256) void k_cvt_wt2(const float* __restrict__ Wa,
                                                 const float* __restrict__ Wb,
                                                 unsigned short* __restrict__ Wt,
                                                 int K, int Ncol){
  __shared__ float t[32][33];
  int half = gridDim.x >> 1;
  int isB = blockIdx.x >= half;
  const float* W = isB ? Wb : Wa;
  unsigned short* out = Wt + (isB ? (size_t)Ncol * K : 0);
  int bx = isB ? blockIdx.x - half : blockIdx.x;
  int by = blockIdx.y;
  int tx = threadIdx.x & 31, ty = threadIdx.x >> 5;
#pragma unroll
  for (int i = 0; i < 4; i++)
    t[ty + i * 8][tx] = W[(size_t)(by * 32 + ty + i * 8) * Ncol + bx * 32 + tx];
  __syncthreads();
#pragma unroll
  for (int i = 0; i < 4; i++)
    out[(size_t)(bx * 32 + ty + i * 8) * K + by * 32 + tx] = f2bf(t[tx][ty + i * 8]);
}

// ---------------- bf16 MFMA GEMM, BK=64 2-phase, 128x256 tile, 8 waves ----------------
// XCD-aware block swizzle: the 4 col-tiles of a row-tile map to consecutive within-XCD
// ranks on ONE XCD (id%8 == XCD round-robin), so the A panel is fetched into that XCD's
// L2 once instead of 4x. Grid must be (4, ceil(rowTiles/8)*8) with rowt guard.
__global__ __launch_bounds__(512) void k_gemm_b64(const unsigned short* __restrict__ A,
                                                  const unsigned short* __restrict__ Wt,
                                                  const float* __restrict__ ba,
                                                  const float* __restrict__ bb,
                                                  int bsplit,
                                                  unsigned short* __restrict__ Cb,
                                                  int M, int K, int Ncol){
  __shared__ unsigned short As[128 * 64];
  __shared__ unsigned short Bs[256 * 64];
  const int tid = threadIdx.x;
  const int w = tid >> 6, lane = tid & 63;
  const int wr = w >> 2, wc = w & 3;
  const int rowTiles = (M + 127) >> 7;
  const int id = blockIdx.x + (gridDim.x * blockIdx.y);
  const int xcd = id & 7;
  const int kk_ = id >> 3;
  const int rowt = (kk_ >> 2) * 8 + xcd;
  const int colt = kk_ & 3;
  if (rowt >= rowTiles) return;
  const int row0 = rowt * 128, col0 = colt * 256;
  const int lr = lane & 15, lk = lane >> 4;

  f32x4 acc[4][4];
#pragma unroll
  for (int i = 0; i < 4; i++)
#pragma unroll
    for (int j = 0; j < 4; j++) acc[i][j] = (f32x4){0.f, 0.f, 0.f, 0.f};

  for (int k0 = 0; k0 < K; k0 += 64){
#pragma unroll
    for (int t = 0; t < 2; t++){
      int g = w * 64 + lane + t * 512;
      int row = g >> 3, slot = g & 7;
      int kq = slot ^ ((row >> 1) & 7);
      int srow = row0 + row; if (srow >= M) srow = M - 1;
      gload16(&A[(size_t)srow * K + k0 + kq * 8], &As[(size_t)(w * 64 + t * 512) * 8]);
    }
#pragma unroll
    for (int t = 0; t < 4; t++){
      int g = w * 64 + lane + t * 512;
      int col = g >> 3, slot = g & 7;
      int kq = slot ^ ((col >> 1) & 7);
      gload16(&Wt[(size_t)(col0 + col) * K + k0 + kq * 8], &Bs[(size_t)(w * 64 + t * 512) * 8]);
    }
    __syncthreads();

#pragma unroll
    for (int ph = 0; ph < 2; ph++){
      bf16x8 af[4], bf_[4];
#pragma unroll
      for (int mi = 0; mi < 4; mi++){
        int rl = wr * 64 + mi * 16 + lr;
        int sl = (ph * 4 + lk) ^ ((rl >> 1) & 7);
        af[mi] = *(const bf16x8*)&As[(rl * 8 + sl) * 8];
      }
#pragma unroll
      for (int ni = 0; ni < 4; ni++){
        int cl = wc * 64 + ni * 16 + lr;
        int sl = (ph * 4 + lk) ^ ((cl >> 1) & 7);
        bf_[ni] = *(const bf16x8*)&Bs[(cl * 8 + sl) * 8];
      }
#pragma unroll
      for (int mi = 0; mi < 4; mi++)
#pragma unroll
        for (int ni = 0; ni < 4; ni++)
          acc[mi][ni] = __builtin_amdgcn_mfma_f32_16x16x32_bf16(af[mi], bf_[ni], acc[mi][ni], 0, 0, 0);
    }
    __syncthreads();
  }

#pragma unroll
  for (int mi = 0; mi < 4; mi++){
#pragma unroll
    for (int ni = 0; ni < 4; ni++){
      int gc = col0 + wc * 64 + ni * 16 + lr;
      float bv = gc < bsplit ? ba[gc] : bb[gc - bsplit];
#pragma unroll
      for (int r = 0; r < 4; r++){
        int gr = row0 + wr * 64 + mi * 16 + lk * 4 + r;
        if (gr < M) Cb[(size_t)gr * Ncol + gc] = f2bf(acc[mi][ni][r] + bv);
      }
    }
  }
}

// ---------------- bf16 MFMA GEMM, 8 waves, 128 x BN tile, BK=32 (L4) ----------------
template<int BN>
__global__ __launch_bounds__(512) void k_gemm_mfma8(const unsigned short* __restrict__ A,
                                                    const unsigned short* __restrict__ Wt,
                                                    const float* __restrict__ ba,
                                                    const float* __restrict__ bb,
                                                    int bsplit,
                                                    unsigned short* __restrict__ Cb,
                                                    int M, int K, int Ncol){
  constexpr int NF = BN / 64;
  __shared__ unsigned short As[128 * 32];
  __shared__ unsigned short Bs[BN * 32];
  const int tid = threadIdx.x;
  const int w = tid >> 6, lane = tid & 63;
  const int wr = w >> 2, wc = w & 3;
  const int row0 = blockIdx.y * 128, col0 = blockIdx.x * BN;
  const int lr = lane & 15, lk = lane >> 4;
  const int swz = (lr >> 1) & 3;

  f32x4 acc[4][NF];
#pragma unroll
  for (int i = 0; i < 4; i++)
#pragma unroll
    for (int j = 0; j < NF; j++) acc[i][j] = (f32x4){0.f, 0.f, 0.f, 0.f};

  for (int k0 = 0; k0 < K; k0 += 32){
    for (int g0 = w * 64; g0 < 512; g0 += 512){
      int g = g0 + lane;
      int row = g >> 2, slot = g & 3;
      int kq = slot ^ ((row >> 1) & 3);
      int srow = row0 + row; if (srow >= M) srow = M - 1;
      gload16(&A[(size_t)srow * K + k0 + kq * 8], &As[(size_t)g0 * 8]);
    }
    for (int g0 = w * 64; g0 < BN * 4; g0 += 512){
      int g = g0 + lane;
      int col = g >> 2, slot = g & 3;
      int kq = slot ^ ((col >> 1) & 3);
      gload16(&Wt[(size_t)(col0 + col) * K + k0 + kq * 8], &Bs[(size_t)g0 * 8]);
    }
    __syncthreads();

    bf16x8 af[4], bf_[NF];
#pragma unroll
    for (int mi = 0; mi < 4; mi++){
      int rl = wr * 64 + mi * 16 + lr;
      af[mi] = *(const bf16x8*)&As[(rl * 4 + (lk ^ swz)) * 8];
    }
#pragma unroll
    for (int ni = 0; ni < NF; ni++){
      int cl = wc * (BN / 4) + ni * 16 + lr;
      bf_[ni] = *(const bf16x8*)&Bs[(cl * 4 + (lk ^ swz)) * 8];
    }
#pragma unroll
    for (int mi = 0; mi < 4; mi++)
#pragma unroll
      for (int ni = 0; ni < NF; ni++)
        acc[mi][ni] = __builtin_amdgcn_mfma_f32_16x16x32_bf16(af[mi], bf_[ni], acc[mi][ni], 0, 0, 0);
    __syncthreads();
  }

#pragma unroll
  for (int mi = 0; mi < 4; mi++){
#pragma unroll
    for (int ni = 0; ni < NF; ni++){
      int gc = col0 + wc * (BN / 4) + ni * 16 + lr;
      float bv = gc < bsplit ? ba[gc] : bb[gc - bsplit];
#pragma unroll
      for (int r = 0; r < 4; r++){
        int gr = row0 + wr * 64 + mi * 16 + lk * 4 + r;
        if (gr < M) Cb[(size_t)gr * Ncol + gc] = f2bf(acc[mi][ni][r] + bv);
      }
    }
  }
}

// ---------------- text-proj GEMM: fp32 A reg-staged -> bf16 LDS; BM=64, Ncol=64 ----------------
__global__ __launch_bounds__(512) void k_gemm_tp(const float* __restrict__ A,
                                                 const unsigned short* __restrict__ Wt,
                                                 const float* __restrict__ bias,
                                                 unsigned short* __restrict__ Cb,
                                                 int M, int K){
  __shared__ unsigned short As[64 * 32];
  __shared__ unsigned short Bs[64 * 32];
  const int tid = threadIdx.x;
  const int w = tid >> 6, lane = tid & 63;
  const int wr = w >> 2, wc = w & 3;
  const int row0 = blockIdx.y * 64;
  const int lr = lane & 15, lk = lane >> 4;
  const int swz = (lr >> 1) & 3;

  f32x4 acc[2];
  acc[0] = (f32x4){0.f, 0.f, 0.f, 0.f};
  acc[1] = (f32x4){0.f, 0.f, 0.f, 0.f};

  for (int k0 = 0; k0 < K; k0 += 32){
    if (tid < 256){
      int g = tid;
      int row = g >> 2, slot = g & 3;
      int kq = slot ^ ((row >> 1) & 3);
      int srow = row0 + row; if (srow >= M) srow = M - 1;
      const float* ap = &A[(size_t)srow * K + k0 + kq * 8];
      float4 f0 = *(const float4*)ap;
      float4 f1 = *(const float4*)(ap + 4);
      bf16x8 v;
      v[0] = (short)f2bf(f0.x); v[1] = (short)f2bf(f0.y);
      v[2] = (short)f2bf(f0.z); v[3] = (short)f2bf(f0.w);
      v[4] = (short)f2bf(f1.x); v[5] = (short)f2bf(f1.y);
      v[6] = (short)f2bf(f1.z); v[7] = (short)f2bf(f1.w);
      *(bf16x8*)&As[(size_t)g * 8] = v;
    } else {
      int g = tid - 256;
      int col = g >> 2, slot = g & 3;
      int kq = slot ^ ((col >> 1) & 3);
      gload16(&Wt[(size_t)col * K + k0 + kq * 8], &Bs[(size_t)g * 8]);
    }
    __syncthreads();

    bf16x8 af[2], bfr;
#pragma unroll
    for (int mi = 0; mi < 2; mi++){
      int rl = wr * 32 + mi * 16 + lr;
      af[mi] = *(const bf16x8*)&As[(rl * 4 + (lk ^ swz)) * 8];
    }
    {
      int cl = wc * 16 + lr;
      bfr = *(const bf16x8*)&Bs[(cl * 4 + (lk ^ swz)) * 8];
    }
    acc[0] = __builtin_amdgcn_mfma_f32_16x16x32_bf16(af[0], bfr, acc[0], 0, 0, 0);
    acc[1] = __builtin_amdgcn_mfma_f32_16x16x32_bf16(af[1], bfr, acc[1], 0, 0, 0);
    __syncthreads();
  }

  int gc = wc * 16 + lr;
  float bv = bias[gc];
#pragma unroll
  for (int mi = 0; mi < 2; mi++)
#pragma unroll
    for (int r = 0; r < 4; r++){
      int gr = row0 + wr * 32 + mi * 16 + lk * 4 + r;
      if (gr < M) Cb[(size_t)gr * 64 + gc] = f2bf(acc[mi][r] + bv);
    }
}

// ---------------- fused GATv2 edge phase, 8 heads (single-wave, dual-state, defer-max) ----------------
// NOTE: plain launch_bounds(256). (256,8) forced 48->32 VGPR => scratch spills (2.2x slower, R12).
__global__ __launch_bounds__(256) void k_gat_fused8(const unsigned short* __restrict__ xlrb,
                                                    const float* __restrict__ att,
                                                    const int* __restrict__ rowptr,
                                                    const int* __restrict__ srcn,
                                                    const float* __restrict__ bias,
                                                    const unsigned short* __restrict__ resb,
                                                    unsigned short* __restrict__ yb,
                                                    int N){
  int node = (blockIdx.x * 256 + threadIdx.x) >> 6;
  int lane = threadIdx.x & 63;
  if (node >= N) return;
  f32x2 xr2[4], av2[4];
  {
    uint4 ur = *(const uint4*)&xlrb[(size_t)node * 1024 + 512 + lane * 8];
    xr2[0] = bfpair(ur.x); xr2[1] = bfpair(ur.y); xr2[2] = bfpair(ur.z); xr2[3] = bfpair(ur.w);
    float4 a0 = *(const float4*)&att[lane * 8];
    float4 a1 = *(const float4*)&att[lane * 8 + 4];
    av2[0] = (f32x2){a0.x, a0.y}; av2[1] = (f32x2){a0.z, a0.w};
    av2[2] = (f32x2){a1.x, a1.y}; av2[3] = (f32x2){a1.z, a1.w};
  }
  int e0 = rowptr[node], e1 = rowptr[node + 1];
  float m0 = -1e30f, s0 = 0.f, m1 = -1e30f, s1 = 0.f;
  f32x2 acc0[4] = {}, acc1[4] = {};

  for (int base = e0; base < e1; base += 64){
    int cnt = min(64, e1 - base);
    int sn = 0;
    if (lane < cnt) sn = srcn[base + lane];
    int k = 0;
    for (; k + 1 < cnt; k += 2){
      int ska = __shfl(sn, k);
      int skb = __shfl(sn, k + 1);
      uint4 ua = *(const uint4*)&xlrb[(size_t)ska * 1024 + lane * 8];
      uint4 ub = *(const uint4*)&xlrb[(size_t)skb * 1024 + lane * 8];
      f32x2 va[4], vb[4];
      va[0] = bfpair(ua.x); va[1] = bfpair(ua.y); va[2] = bfpair(ua.z); va[3] = bfpair(ua.w);
      vb[0] = bfpair(ub.x); vb[1] = bfpair(ub.y); vb[2] = bfpair(ub.z); vb[3] = bfpair(ub.w);
      f32x2 da = (f32x2){0.f, 0.f}, db = (f32x2){0.f, 0.f};
#pragma unroll
      for (int j = 0; j < 4; j++){
        f32x2 ta = va[j] + xr2[j];
        f32x2 tb = vb[j] + xr2[j];
        ta = vmax2(ta, ta * NEG_SLOPE);
        tb = vmax2(tb, tb * NEG_SLOPE);
        da += ta * av2[j];
        db += tb * av2[j];
      }
      float suma = da.x + da.y, sumb = db.x + db.y;
      suma += __shfl_xor(suma, 1); sumb += __shfl_xor(sumb, 1);
      suma += __shfl_xor(suma, 2); sumb += __shfl_xor(sumb, 2);
      suma += __shfl_xor(suma, 4); sumb += __shfl_xor(sumb, 4);
      if (__builtin_expect(__any(suma > m0 + THR), 0)){
        float mn = fmaxf(m0, suma);
        float cs = __expf(m0 - mn);
        float p  = __expf(suma - mn);
        s0 = s0 * cs + p;
#pragma unroll
        for (int j = 0; j < 4; j++) acc0[j] = acc0[j] * cs + va[j] * p;
        m0 = mn;
      } else {
        float p = __expf(suma - m0);
        s0 += p;
#pragma unroll
        for (int j = 0; j < 4; j++) acc0[j] += va[j] * p;
      }
      if (__builtin_expect(__any(sumb > m1 + THR), 0)){
        float mn = fmaxf(m1, sumb);
        float cs = __expf(m1 - mn);
        float p  = __expf(sumb - mn);
        s1 = s1 * cs + p;
#pragma unroll
        for (int j = 0; j < 4; j++) acc1[j] = acc1[j] * cs + vb[j] * p;
        m1 = mn;
      } else {
        float p = __expf(sumb - m1);
        s1 += p;
#pragma unroll
        for (int j = 0; j < 4; j++) acc1[j] += vb[j] * p;
      }
    }
    if (k < cnt){
      int ska = __shfl(sn, k);
      uint4 ua = *(const uint4*)&xlrb[(size_t)ska * 1024 + lane * 8];
      f32x2 va[4];
      va[0] = bfpair(ua.x); va[1] = bfpair(ua.y); va[2] = bfpair(ua.z); va[3] = bfpair(ua.w);
      f32x2 da = (f32x2){0.f, 0.f};
#pragma unroll
      for (int j = 0; j < 4; j++){
        f32x2 ta = va[j] + xr2[j];
        ta = vmax2(ta, ta * NEG_SLOPE);
        da += ta * av2[j];
      }
      float suma = da.x + da.y;
      suma += __shfl_xor(suma, 1);
      suma += __shfl_xor(suma, 2);
      suma += __shfl_xor(suma, 4);
      if (__builtin_expect(__any(suma > m0 + THR), 0)){
        float mn = fmaxf(m0, suma);
        float cs = __expf(m0 - mn);
        float p  = __expf(suma - mn);
        s0 = s0 * cs + p;
#pragma unroll
        for (int j = 0; j < 4; j++) acc0[j] = acc0[j] * cs + va[j] * p;
        m0 = mn;
      } else {
        float p = __expf(suma - m0);
        s0 += p;
#pragma unroll
        for (int j = 0; j < 4; j++) acc0[j] += va[j] * p;
      }
    }
  }
  float m = fmaxf(m0, m1);
  float c0 = __expf(m0 - m), c1 = __expf(m1 - m);
  float s = s0 * c0 + s1 * c1;
  float inv = 1.f / s;
  float4 b0 = *(const float4*)&bias[lane * 8];
  float4 b1 = *(const float4*)&bias[lane * 8 + 4];
  f32x2 bi2[4] = {(f32x2){b0.x, b0.y}, (f32x2){b0.z, b0.w},
                  (f32x2){b1.x, b1.y}, (f32x2){b1.z, b1.w}};
  f32x2 re2[4] = {};
  size_t o = (size_t)node * 512 + lane * 8;
  if (resb){
    uint4 rr = *(const uint4*)&resb[o];
    re2[0] = bfpair(rr.x); re2[1] = bfpair(rr.y); re2[2] = bfpair(rr.z); re2[3] = bfpair(rr.w);
  }
  bf16x8 ov;
#pragma unroll
  for (int j = 0; j < 4; j++){
    f32x2 r = (acc0[j] * c0 + acc1[j] * c1) * inv + bi2[j] + re2[j];
    ov[2 * j]     = (short)f2bf(r.x);
    ov[2 * j + 1] = (short)f2bf(r.y);
  }
  *(bf16x8*)&yb[o] = ov;
}

// ---------------- fused GATv2 edge phase, 1 head, OD=64 (layer 4, quad-state) ----------------
__global__ __launch_bounds__(256) void k_gat_fused1(const unsigned short* __restrict__ xlr,
                                                    const float* __restrict__ att,
                                                    const int* __restrict__ rowptr,
                                                    const int* __restrict__ srcn,
                                                    const float* __restrict__ bias,
                                                    unsigned short* __restrict__ yb4,
                                                    int N){
  int node = (blockIdx.x * 256 + threadIdx.x) >> 6;
  int lane = threadIdx.x & 63;
  if (node >= N) return;
  float xrv = bf2f(xlr[(size_t)node * 128 + 64 + lane]);
  float attv = att[lane];
  int e0 = rowptr[node], e1 = rowptr[node + 1];
  float m[4] = {-1e30f, -1e30f, -1e30f, -1e30f};
  float s[4] = {0.f, 0.f, 0.f, 0.f};
  float acc[4] = {0.f, 0.f, 0.f, 0.f};
  for (int base = e0; base < e1; base += 64){
    int cnt = min(64, e1 - base);
    int sn = 0;
    if (lane < cnt) sn = srcn[base + lane];
    for (int k = 0; k < cnt; k += 4){
#pragma unroll
      for (int j = 0; j < 4; j++){
        if (k + j < cnt){
          int sk = __shfl(sn, k + j);
          float v = bf2f(xlr[(size_t)sk * 128 + lane]);
          float t = v + xrv;
          t = fmaxf(t, t * NEG_SLOPE);
          float sum = wred_sum(t * attv);
          if (sum > m[j] + THR){
            float mn = fmaxf(m[j], sum);
            float cs = __expf(m[j] - mn);
            float p  = __expf(sum - mn);
            s[j] = s[j] * cs + p;
            acc[j] = acc[j] * cs + p * v;
            m[j] = mn;
          } else {
            float p = __expf(sum - m[j]);
            s[j] += p;
            acc[j] += p * v;
          }
        }
      }
    }
  }
  float mm = fmaxf(fmaxf(m[0], m[1]), fmaxf(m[2], m[3]));
  float st = 0.f, at = 0.f;
#pragma unroll
  for (int j = 0; j < 4; j++){
    float c = __expf(m[j] - mm);
    st += s[j] * c;
    at += acc[j] * c;
  }
  yb4[(size_t)node * 64 + lane] = f2bf(at / st + bias[lane]);
}

// ---------------- GraphNorm: chunked stats (bf16 in) -> coef -> apply (bf16 in/out + cat) ----------------
#define NCHUNK 16
__global__ __launch_bounds__(256) void k_gnorm_stats(const unsigned short* __restrict__ y,
                                                     const int* __restrict__ ptrg,
                                                     float* __restrict__ psum,
                                                     float* __restrict__ psq,
                                                     int OD){
  int g = blockIdx.x, chunk = blockIdx.z;
  int lane = threadIdx.x & 63, sub = threadIdx.x >> 6;
  int c = blockIdx.y * 64 + lane;
  int lo = ptrg[g], hi = ptrg[g + 1], len = hi - lo;
  int c0 = lo + (len * chunk) / NCHUNK, c1 = lo + (len * (chunk + 1)) / NCHUNK;
  float s = 0.f, q = 0.f;
  for (int i = c0 + sub; i < c1; i += 4){
    float v = bf2f(y[(size_t)i * OD + c]);
    s += v; q += v * v;
  }
  __shared__ float sm[4][64], sq2[4][64];
  sm[sub][lane] = s; sq2[sub][lane] = q;
  __syncthreads();
  if (sub == 0){
    s = sm[0][lane] + sm[1][lane] + sm[2][lane] + sm[3][lane];
    q = sq2[0][lane] + sq2[1][lane] + sq2[2][lane] + sq2[3][lane];
    size_t o = (size_t)(g * NCHUNK + chunk) * OD + c;
    psum[o] = s; psq[o] = q;
  }
}

__global__ __launch_bounds__(256) void k_gnorm_coef(const float* __restrict__ psum,
                                                    const float* __restrict__ psq,
                                                    const float* __restrict__ w,
                                                    const float* __restrict__ b,
                                                    const float* __restrict__ ms,
                                                    const int* __restrict__ ptrg,
                                                    float* __restrict__ cA,
                                                    float* __restrict__ cC,
                                                    int OD){
  int g = blockIdx.x;
  int len = ptrg[g + 1] - ptrg[g];
  float inv_n = 1.f / (float)len;
  for (int c = threadIdx.x; c < OD; c += 256){
    float s = 0.f, q = 0.f;
    for (int k = 0; k < NCHUNK; k++){
      size_t o = (size_t)(g * NCHUNK + k) * OD + c;
      s += psum[o]; q += psq[o];
    }
    float mean = s * inv_n, ey2 = q * inv_n;
    float m = ms[c];
    float var = ey2 - mean * mean * (2.f * m - m * m);
    float inv = rsqrtf(var + EPSI);
    float A = w[c] * inv;
    cA[(size_t)g * OD + c] = A;
    cC[(size_t)g * OD + c] = b[c] - A * m * mean;
  }
}

__global__ __launch_bounds__(256) void k_gnorm_apply(const unsigned short* __restrict__ y,
                                                     const int* __restrict__ batch,
                                                     const float* __restrict__ cA,
                                                     const float* __restrict__ cC,
                                                     unsigned short* __restrict__ outb,
                                                     const int* __restrict__ ptrg,
                                                     float* __restrict__ cat,
                                                     int catoff, int FD,
                                                     int OD, int total4, int do_elu){
  int idx = blockIdx.x * 256 + threadIdx.x;
  if (idx >= total4) return;
  int od4 = OD >> 2;
  int node = idx / od4;
  int c = (idx - node * od4) << 2;
  int g = batch[node];
  ushort4 uv = ((const ushort4*)y)[idx];
  float4 v = make_float4(bf2f(uv.x), bf2f(uv.y), bf2f(uv.z), bf2f(uv.w));
  float4 A = *(const float4*)&cA[(size_t)g * OD + c];
  float4 Cc = *(const float4*)&cC[(size_t)g * OD + c];
  float4 r;
  r.x = A.x * v.x + Cc.x;
  r.y = A.y * v.y + Cc.y;
  r.z = A.z * v.z + Cc.z;
  r.w = A.w * v.w + Cc.w;
  if (do_elu){
    r.x = r.x > 0.f ? r.x : expf(r.x) - 1.f;
    r.y = r.y > 0.f ? r.y : expf(r.y) - 1.f;
    r.z = r.z > 0.f ? r.z : expf(r.z) - 1.f;
    r.w = r.w > 0.f ? r.w : expf(r.w) - 1.f;
  }
  ushort4 ob;
  ob.x = f2bf(r.x); ob.y = f2bf(r.y); ob.z = f2bf(r.z); ob.w = f2bf(r.w);
  ((ushort4*)outb)[idx] = ob;
  if (node == ptrg[g])
    *(float4*)&cat[(size_t)g * FD + catoff + c] = r;
}

// ---------------- final linear on 50 summary rows ----------------
__global__ __launch_bounds__(256) void k_final(const float* __restrict__ cat,
                                               const float* __restrict__ lin_w,
                                               const float* __restrict__ lin_b,
                                               float* __restrict__ out, int FD){
  int g = blockIdx.x;
  float s = 0.f;
  for (int c = threadIdx.x; c < FD; c += 256) s += cat[(size_t)g * FD + c] * lin_w[c];
  s = wred_sum(s);
  __shared__ float sm[4];
  if ((threadIdx.x & 63) == 0) sm[threadIdx.x >> 6] = s;
  __syncthreads();
  if (threadIdx.x == 0) out[g] = sm[0] + sm[1] + sm[2] + sm[3] + lin_b[0];
}

extern "C" void kernel_launch(void* const* d_in, const int* in_sizes, int n_in,
                              void* d_out, int out_size, void* d_ws, size_t ws_size,
                              hipStream_t stream) {
  const int TD = 768, HC = 64, H = 8;
  const float* x     = (const float*)d_in[0];
  const int*   ei    = (const int*)d_in[1];
  const int*   batch = (const int*)d_in[2];
  const int*   ptrg  = (const int*)d_in[3];
  const float* tp_w  = (const float*)d_in[4];
  const float* tp_b  = (const float*)d_in[5];
  const float* lin_w = (const float*)d_in[6];
  const float* lin_b = (const float*)d_in[7];
  const float* cw[4][6];
  for (int l = 0; l < 4; l++)
    for (int j = 0; j < 6; j++) cw[l][j] = (const float*)d_in[8 + 6 * l + j];
  const float* nw[4][3];
  for (int l = 0; l < 4; l++)
    for (int j = 0; j < 3; j++) nw[l][j] = (const float*)d_in[32 + 3 * l + j];

  const int N  = in_sizes[0] / TD;   // 20000
  const int E  = in_sizes[1] / 2;    // 240000
  const int EP = E + N;              // 260000
  const int G  = in_sizes[3] - 1;    // 50
  const int FD = 3 * HC * H + HC;    // 1600

  char* wsp = (char*)d_ws;
  size_t off = 0;
  auto alloc = [&](size_t b) -> void* {
    void* p = wsp + off;
    off += (b + 255) & ~(size_t)255;
    return p;
  };
  unsigned short* xlrb = (unsigned short*)alloc((size_t)N * 1024 * 2);
  unsigned short* yb   = (unsigned short*)alloc((size_t)N * 512 * 2);
  unsigned short* actA = (unsigned short*)alloc((size_t)N * 512 * 2);
  unsigned short* h0h  = (unsigned short*)alloc((size_t)N * 64 * 2);
  int*   rowptr= (int*)alloc((size_t)(N + 1) * 4);
  int*   cursor= (int*)alloc((size_t)N * 4);
  int*   srcn  = (int*)alloc((size_t)EP * 4);
  float* cat   = (float*)alloc((size_t)G * FD * 4);
  float* psum  = (float*)alloc((size_t)G * NCHUNK * 512 * 4);
  float* psq   = (float*)alloc((size_t)G * NCHUNK * 512 * 4);
  float* cA    = (float*)alloc((size_t)G * 512 * 4);
  float* cC    = (float*)alloc((size_t)G * 512 * 4);
  unsigned short* WtLR = (unsigned short*)alloc((size_t)1024 * 512 * 2);
  unsigned short* WtTP = (unsigned short*)alloc((size_t)64 * 768 * 2);
  unsigned short* Wt4  = (unsigned short*)alloc((size_t)128 * 512 * 2);
  (void)ws_size; (void)n_in; (void)out_size;

  float* out = (float*)d_out;

  unsigned short* xlr4b = xlrb;
  unsigned short* yb4   = yb;

  // ---- CSR build ----
  hipMemsetAsync(cursor, 0, (size_t)N * 4, stream);
  int eblk = (EP + 255) / 256;
  k_count<<<eblk, 256, 0, stream>>>(ei, cursor, E, EP);
  k_scan<<<1, 256, 0, stream>>>(cursor, rowptr, N);
  k_fill<<<eblk, 256, 0, stream>>>(ei, cursor, srcn, E, EP);

  const int mfmaRows = (N + 127) / 128;               // 157
  const int swzRows  = ((mfmaRows + 7) / 8) * 8;      // 160 (XCD-bijective padding)
  const int tpRows   = (N + 63) / 64;                 // 313
  const int nodeBlocks = (N + 3) / 4;

  // ---- text projection: fp32-A MFMA, BM=64 ----
  k_cvt_wt<<<dim3(2, TD / 32), 256, 0, stream>>>(tp_w, WtTP, TD, 64);
  k_gemm_tp<<<dim3(1, tpRows), 512, 0, stream>>>(x, WtTP, tp_b, h0h, N, TD);

  auto layer8 = [&](const unsigned short* actbf, int Kin, int l,
                    const unsigned short* resb, int catoff){
    k_cvt_wt2<<<dim3(32, Kin / 32), 256, 0, stream>>>(cw[l][0], cw[l][2], WtLR, Kin, 512);
    k_gemm_b64<<<dim3(4, swzRows), 512, 0, stream>>>(actbf, WtLR, cw[l][1], cw[l][3], 512,
                                                     xlrb, N, Kin, 1024);
    k_gat_fused8<<<nodeBlocks, 256, 0, stream>>>(xlrb, cw[l][4], rowptr, srcn,
                                                 cw[l][5], resb, yb, N);
    k_gnorm_stats<<<dim3(G, 8, NCHUNK), 256, 0, stream>>>(yb, ptrg, psum, psq, 512);
    k_gnorm_coef<<<G, 256, 0, stream>>>(psum, psq, nw[l][0], nw[l][1], nw[l][2], ptrg, cA, cC, 512);
    int total4 = N * 128;
    k_gnorm_apply<<<(total4 + 255) / 256, 256, 0, stream>>>(yb, batch, cA, cC, actA,
                                                            ptrg, cat, catoff, FD,
                                                            512, total4, 1);
  };

  layer8(h0h,  64,  0, nullptr, 0);
  layer8(actA, 512, 1, actA,    512);
  layer8(actA, 512, 2, actA,    1024);

  // ---- layer 4: combined xl|xr MFMA (Ncol=128) + fused edge + gnorm ----
  k_cvt_wt2<<<dim3(4, 16), 256, 0, stream>>>(cw[3][0], cw[3][2], Wt4, 512, 64);
  k_gemm_mfma8<128><<<dim3(1, mfmaRows), 512, 0, stream>>>(actA, Wt4, cw[3][1], cw[3][3], 64,
                                                           xlr4b, N, 512, 128);
  k_gat_fused1<<<nodeBlocks, 256, 0, stream>>>(xlr4b, cw[3][4], rowptr, srcn,
                                               cw[3][5], yb4, N);
  k_gnorm_stats<<<dim3(G, 1, NCHUNK), 256, 0, stream>>>(yb4, ptrg, psum, psq, 64);
  k_gnorm_coef<<<G, 256, 0, stream>>>(psum, psq, nw[3][0], nw[3][1], nw[3][2], ptrg, cA, cC, 64);
  k_gnorm_apply<<<(N * 16 + 255) / 256, 256, 0, stream>>>(yb4, batch, cA, cC, h0h,
                                                          ptrg, cat, 1536, FD,
                                                          64, N * 16, 0);

  k_final<<<G, 256, 0, stream>>>(cat, lin_w, lin_b, out, FD);
}